// Round 1
// baseline (309.584 us; speedup 1.0000x reference)
//
#include <hip/hip_runtime.h>
#include <hip/hip_bf16.h>
#include <cstdint>

// ---------------------------------------------------------------------------
// SelfAttention: q,k,v = x@W{q,k,v}^T + b ; P = softmax(qk^T/sqrt(H)) ; out = P@v
// B=4, S=2048, H=I=1024. fp32 I/O, bf16 MFMA internally.
// R5: 256x128x64 GEMM core, 8 waves (4Mx2N), 3-deep LDS pipeline (144KB),
//     counted s_waitcnt vmcnt(6) at K-tile boundaries (never 0 in main loop),
//     raw s_barrier + sched_barrier fences, setprio around MFMA cluster.
//     Same verified XOR chunk swizzle (pre-swizzled global src, linear
//     global_load_lds dest, swizzled ds_read_b128) and epilogue mappings.
// ---------------------------------------------------------------------------

typedef __bf16 bf16x8 __attribute__((ext_vector_type(8)));
typedef float  f32x4  __attribute__((ext_vector_type(4)));

__device__ __forceinline__ void load_lds16(const __bf16* g, __bf16* l) {
    __builtin_amdgcn_global_load_lds(
        (const __attribute__((address_space(1))) void*)g,
        (__attribute__((address_space(3))) void*)l,
        16, 0, 0);
}

// ------------- merged fp32->bf16 converts + bias pack (1 launch) -----------
__global__ __launch_bounds__(256) void cvt_all(
        const float* __restrict__ x,
        const float* __restrict__ wq, const float* __restrict__ wk,
        const float* __restrict__ wv,
        const float* __restrict__ bq, const float* __restrict__ bk,
        const float* __restrict__ bv,
        __bf16* __restrict__ xb, __bf16* __restrict__ wb,
        float* __restrict__ bias3) {
    const long NX = 1048576, NW = 131072;
    long i = (long)blockIdx.x * 256 + threadIdx.x;
    const float* src; __bf16* dst; long c;
    if (i < NX) { src = x; dst = xb; c = i; }
    else if (i < NX + 3 * NW) {
        long j = i - NX;
        src = (j < NW) ? wq : (j < 2 * NW) ? wk : wv;
        c = j % NW;
        dst = wb + (j / NW) * (NW * 8);
    } else if (i < NX + 3 * NW + 384) {
        long cidx = i - (NX + 3 * NW);
        int seg = (int)(cidx >> 7);
        const float* bs = (seg == 0) ? bq : (seg == 1) ? bk : bv;
        long off = (cidx & 127) * 8;
        float4 a = *(const float4*)(bs + off);
        float4 b = *(const float4*)(bs + off + 4);
        *(float4*)(bias3 + cidx * 8)     = a;
        *(float4*)(bias3 + cidx * 8 + 4) = b;
        return;
    } else return;
    const float4* s4 = (const float4*)src;
    float4 a = s4[2 * c], b = s4[2 * c + 1];
    bf16x8 o;
    o[0] = (__bf16)a.x; o[1] = (__bf16)a.y; o[2] = (__bf16)a.z; o[3] = (__bf16)a.w;
    o[4] = (__bf16)b.x; o[5] = (__bf16)b.y; o[6] = (__bf16)b.z; o[7] = (__bf16)b.w;
    ((bf16x8*)dst)[c] = o;
}

// ---------------- NT bf16 GEMM: C[m,n] = sum_k A[m,k] * Bt[n,k] ------------
// 256x128 tile, BK=64, 512 threads = 8 waves (4Mx2N), per-wave 64x64 (4x4
// frags of 16x16x32 MFMA). 3 LDS buffers of (A 32KB + B 16KB) = 144KB.
// Pipeline: during tile t, issue tile t+2's 6 global_load_lds; boundary is
// s_waitcnt vmcnt(6) + s_barrier (tail: vmcnt(0) once). LDS chunk (row,cs)
// holds chunk cg = cs ^ (row&7): conflict-free ds_read_b128, linear
// global_load_lds dest with pre-swizzled global source.
// MODE 0: fused QKV. n<2048 -> bf16=acc+bias to C0/C1 [m][n&1023];
//         n>=2048 -> V: LDS-transposed, written as vt[h][t] to C2.
// MODE 1: f32 = acc * scale  (scores)
// MODE 2: f32 = acc          (PV)
template <int MODE>
__global__ __launch_bounds__(512, 2) void gemm_nt8(
        const __bf16* __restrict__ A, const __bf16* __restrict__ Bt,
        void* __restrict__ C0, void* __restrict__ C1, void* __restrict__ C2,
        const float* __restrict__ bias,
        int lda, int ldb, int ldc, long sA, long sB, long sC,
        int K, float scale) {
    __shared__ __bf16 smem[73728];       // 3 x (16384 A + 8192 B) bf16 = 144KB

    const int tid  = threadIdx.x;
    const int lane = tid & 63;
    const int wave = tid >> 6;
    const int mblk = blockIdx.y * 256;
    const int nblk = blockIdx.x * 128;
    const int z    = blockIdx.z;
    A  += (long)z * sA;
    Bt += (long)z * sB;

    const int wmb  = (wave >> 1) * 64;   // 0,64,128,192
    const int wnb  = (wave & 1) * 64;    // 0,64
    const int rsel = lane & 15;
    const int quad = lane >> 4;

    f32x4 zero = {0.f, 0.f, 0.f, 0.f};
    f32x4 acc[4][4];
#pragma unroll
    for (int i = 0; i < 4; ++i)
#pragma unroll
        for (int j = 0; j < 4; ++j) acc[i][j] = zero;

    // staging geometry: s = it*512 + tid; row = s>>3; 16B chunk cg pre-swizzled
    int srow[4], scg[4];
#pragma unroll
    for (int it = 0; it < 4; ++it) {
        int s = it * 512 + tid;
        srow[it] = s >> 3;
        scg[it]  = ((s & 7) ^ (srow[it] & 7)) * 8;
    }

    auto STAGE = [&](int t, int bufb) {
        const long k0 = (long)t << 6;
        __bf16* lAb = smem + bufb * 24576;
        __bf16* lBb = lAb + 16384;
#pragma unroll
        for (int it = 0; it < 4; ++it)
            load_lds16(A + (long)(mblk + srow[it]) * lda + k0 + scg[it],
                       lAb + (it * 512 + tid) * 8);
#pragma unroll
        for (int it = 0; it < 2; ++it)
            load_lds16(Bt + (long)(nblk + srow[it]) * ldb + k0 + scg[it],
                       lBb + (it * 512 + tid) * 8);
    };

    const int NT = K >> 6;

    // prologue: tiles 0,1 in flight; wait for tile 0 (6 of tile 1 outstanding)
    STAGE(0, 0);
    STAGE(1, 1);
    asm volatile("s_waitcnt vmcnt(6)" ::: "memory");
    __builtin_amdgcn_s_barrier();
    __builtin_amdgcn_sched_barrier(0);

    int cur = 0;
    for (int t = 0; t < NT; ++t) {
        __bf16* lA = smem + cur * 24576;
        __bf16* lB = lA + 16384;

        bf16x8 fa0[4], fa1[4], fb0[4], fb1[4];
#pragma unroll
        for (int i = 0; i < 4; ++i) {
            const int ra = wmb + i * 16 + rsel;
            const int rx = ra * 8, sw = ra & 7;
            fa0[i] = *(const bf16x8*)&lA[(rx + (quad ^ sw)) * 8];
            fa1[i] = *(const bf16x8*)&lA[(rx + ((quad + 4) ^ sw)) * 8];
        }
#pragma unroll
        for (int j = 0; j < 4; ++j) {
            const int rb = wnb + j * 16 + rsel;
            const int rx = rb * 8, sw = rb & 7;
            fb0[j] = *(const bf16x8*)&lB[(rx + (quad ^ sw)) * 8];
            fb1[j] = *(const bf16x8*)&lB[(rx + ((quad + 4) ^ sw)) * 8];
        }

        int nxt = cur + 2; if (nxt >= 3) nxt -= 3;
        if (t + 2 < NT) STAGE(t + 2, nxt);   // into buffer last read at t-1

        __builtin_amdgcn_s_setprio(1);
#pragma unroll
        for (int i = 0; i < 4; ++i)
#pragma unroll
            for (int j = 0; j < 4; ++j)
                acc[i][j] = __builtin_amdgcn_mfma_f32_16x16x32_bf16(
                    fa0[i], fb0[j], acc[i][j], 0, 0, 0);
#pragma unroll
        for (int i = 0; i < 4; ++i)
#pragma unroll
            for (int j = 0; j < 4; ++j)
                acc[i][j] = __builtin_amdgcn_mfma_f32_16x16x32_bf16(
                    fa1[i], fb1[j], acc[i][j], 0, 0, 0);
        __builtin_amdgcn_s_setprio(0);

        if (t + 1 < NT) {
            // retire tile t+1's 6 loads (oldest); keep tile t+2's 6 in flight
            if (t + 2 < NT) asm volatile("s_waitcnt vmcnt(6)" ::: "memory");
            else            asm volatile("s_waitcnt vmcnt(0)" ::: "memory");
            __builtin_amdgcn_s_barrier();
            __builtin_amdgcn_sched_barrier(0);
        }
        cur += 1; if (cur == 3) cur = 0;
    }

    // epilogue: lane holds C[m = wmb+i*16+quad*4+r][n = wnb+j*16+rsel]
    const int rq = quad * 4;
    if constexpr (MODE == 0) {
        if (nblk >= 2048) {
            // ---- V path: transpose 256(t) x 128(h) tile via LDS ----
            __syncthreads();               // all waves done with smem buffers
            __bf16* tbuf = smem;           // [n_loc][32 chunks of 8], swizzled
#pragma unroll
            for (int i = 0; i < 4; ++i) {
#pragma unroll
                for (int j = 0; j < 4; ++j) {
                    const int n_loc = wnb + j * 16 + rsel;       // 0..127
                    const float bv = bias[nblk + n_loc];
                    const int m_loc = wmb + i * 16 + rq;         // +r, r=0..3
                    const int c  = m_loc >> 3;                   // 0..31
                    const int cs = c ^ (n_loc & 31);
                    __bf16* dst = &tbuf[n_loc * 256 + cs * 8 + (m_loc & 7)];
                    __bf16 tmp[4];
#pragma unroll
                    for (int r = 0; r < 4; ++r) tmp[r] = (__bf16)(acc[i][j][r] + bv);
                    *(uint64_t*)dst = *(const uint64_t*)tmp;
                }
            }
            __syncthreads();
            // store: half-wave covers one full 512B row -> coalesced
            {
                const long b  = mblk >> 11;                      // batch
                const long t0 = mblk & 2047;
                const long hbase = nblk - 2048;
                __bf16* vt = (__bf16*)C2 + b * (2048L * 1024) + t0;
#pragma unroll
                for (int pass = 0; pass < 8; ++pass) {
                    int h_loc = pass * 16 + wave * 2 + (lane >> 5);  // 0..127
                    int c  = lane & 31;
                    int cs = c ^ (h_loc & 31);
                    bf16x8 vchunk = *(const bf16x8*)&tbuf[h_loc * 256 + cs * 8];
                    *(bf16x8*)(vt + (hbase + h_loc) * 2048 + c * 8) = vchunk;
                }
            }
        } else {
            // ---- Q/K path: normal [m][n] bf16 store ----
#pragma unroll
            for (int i = 0; i < 4; ++i) {
#pragma unroll
                for (int j = 0; j < 4; ++j) {
                    const int n = nblk + wnb + j * 16 + rsel;
                    __bf16* C = (n < 1024) ? (__bf16*)C0 : (__bf16*)C1;
                    const int col = n & 1023;
                    float bv = bias[n];
#pragma unroll
                    for (int r = 0; r < 4; ++r) {
                        int m = mblk + wmb + i * 16 + rq + r;
                        C[(long)m * ldc + col] = (__bf16)(acc[i][j][r] + bv);
                    }
                }
            }
        }
    } else {
        float* C = (float*)C0 + (long)z * sC;
#pragma unroll
        for (int i = 0; i < 4; ++i) {
#pragma unroll
            for (int j = 0; j < 4; ++j) {
                const int n = nblk + wnb + j * 16 + rsel;
#pragma unroll
                for (int r = 0; r < 4; ++r) {
                    int m = mblk + wmb + i * 16 + rq + r;
                    if constexpr (MODE == 1)
                        C[(long)m * ldc + n] = acc[i][j][r] * scale;
                    else
                        C[(long)m * ldc + n] = acc[i][j][r];
                }
            }
        }
    }
}

// ---------------- row softmax over 2048 floats, in-place + bf16 copy -------
__global__ __launch_bounds__(256) void softmax_rows(
        float* __restrict__ P, __bf16* __restrict__ Pb) {
    const long row = blockIdx.x;
    float*  p  = P  + row * 2048;
    __bf16* pb = Pb + row * 2048;
    const int tid  = threadIdx.x;
    const int lane = tid & 63;
    const int wave = tid >> 6;

    float4 v0 = ((const float4*)p)[tid * 2];
    float4 v1 = ((const float4*)p)[tid * 2 + 1];
    float e[8] = {v0.x, v0.y, v0.z, v0.w, v1.x, v1.y, v1.z, v1.w};

    float mx = e[0];
#pragma unroll
    for (int i = 1; i < 8; ++i) mx = fmaxf(mx, e[i]);
#pragma unroll
    for (int o = 1; o < 64; o <<= 1) mx = fmaxf(mx, __shfl_xor(mx, o, 64));

    __shared__ float redm[4], reds[4];
    if (lane == 0) redm[wave] = mx;
    __syncthreads();
    mx = fmaxf(fmaxf(redm[0], redm[1]), fmaxf(redm[2], redm[3]));

    float sum = 0.f;
#pragma unroll
    for (int i = 0; i < 8; ++i) { e[i] = __expf(e[i] - mx); sum += e[i]; }
#pragma unroll
    for (int o = 1; o < 64; o <<= 1) sum += __shfl_xor(sum, o, 64);
    if (lane == 0) reds[wave] = sum;
    __syncthreads();
    sum = reds[0] + reds[1] + reds[2] + reds[3];
    const float inv = 1.f / sum;

    float4 o0, o1;
    o0.x = e[0] * inv; o0.y = e[1] * inv; o0.z = e[2] * inv; o0.w = e[3] * inv;
    o1.x = e[4] * inv; o1.y = e[5] * inv; o1.z = e[6] * inv; o1.w = e[7] * inv;
    ((float4*)p)[tid * 2]     = o0;
    ((float4*)p)[tid * 2 + 1] = o1;
    bf16x8 ob;
    ob[0] = (__bf16)o0.x; ob[1] = (__bf16)o0.y; ob[2] = (__bf16)o0.z; ob[3] = (__bf16)o0.w;
    ob[4] = (__bf16)o1.x; ob[5] = (__bf16)o1.y; ob[6] = (__bf16)o1.z; ob[7] = (__bf16)o1.w;
    ((bf16x8*)pb)[tid] = ob;
}

// ---------------------------------------------------------------------------
extern "C" void kernel_launch(void* const* d_in, const int* in_sizes, int n_in,
                              void* d_out, int out_size, void* d_ws, size_t ws_size,
                              hipStream_t stream) {
    const float* x  = (const float*)d_in[0];
    const float* Wq = (const float*)d_in[1];
    const float* bq = (const float*)d_in[2];
    const float* Wk = (const float*)d_in[3];
    const float* bk = (const float*)d_in[4];
    const float* Wv = (const float*)d_in[5];
    const float* bv = (const float*)d_in[6];

    const int  S = 2048, H = 1024, I = 1024, B = 4;
    const long MS = (long)B * S;
    float* out_ws  = (float*)d_out;
    float* out_att = (float*)d_out + (long)B * S * H;

    char* w = (char*)d_ws;
    __bf16* x_bf   = (__bf16*)w; w += MS * I * 2;
    __bf16* wqkv   = (__bf16*)w; w += (long)3 * H * I * 2;
    float*  bias3  = (float*)w;  w += 4096 * 4;
    __bf16* q_bf   = (__bf16*)w; w += MS * H * 2;
    __bf16* k_bf   = (__bf16*)w; w += MS * H * 2;
    __bf16* vt_bf  = (__bf16*)w; w += MS * H * 2;
    __bf16* p_bf   = (__bf16*)w; w += (long)B * S * S * 2;

    // 1) all converts + bias pack
    {
        long tot = 1048576 + 3 * 131072 + 384;
        cvt_all<<<dim3((unsigned)((tot + 255) / 256)), dim3(256), 0, stream>>>(
            x, Wq, Wk, Wv, bq, bk, bv, x_bf, wqkv, bias3);
    }

    // 2) fused QKV projection (V pre-transposed): M=8192, N=3072, K=1024
    gemm_nt8<0><<<dim3(24, 32, 1), dim3(512), 0, stream>>>(
        x_bf, wqkv, q_bf, k_bf, vt_bf, bias3,
        1024, 1024, 1024, 0, 0, 0, 1024, 1.f);

    // 3) scores = Q K^T * 1/32 -> fp32 into attn-weights output region
    gemm_nt8<1><<<dim3(16, 8, 4), dim3(512), 0, stream>>>(
        q_bf, k_bf, out_att, nullptr, nullptr, nullptr,
        1024, 1024, 2048, (long)S * H, (long)S * H, (long)S * S, 1024, 0.03125f);

    // 4) softmax rows in-place (+ bf16 copy for PV)
    softmax_rows<<<dim3(8192), dim3(256), 0, stream>>>(out_att, p_bf);

    // 5) weighted_sum = P V : M=2048, N=1024, K=2048 per batch
    gemm_nt8<2><<<dim3(8, 8, 4), dim3(512), 0, stream>>>(
        p_bf, vt_bf, out_ws, nullptr, nullptr, nullptr,
        2048, 2048, 1024, (long)S * S, (long)S * H, (long)S * H, 2048, 1.f);
}

// Round 2
// 309.506 us; speedup vs baseline: 1.0002x; 1.0002x over previous
//
#include <hip/hip_runtime.h>
#include <hip/hip_bf16.h>
#include <cstdint>

// ---------------------------------------------------------------------------
// SelfAttention: q,k,v = x@W{q,k,v}^T + b ; P = softmax(qk^T/sqrt(H)) ; out = P@v
// B=4, S=2048, H=I=1024. fp32 I/O, bf16 MFMA internally.
// R6: 256x256 8-phase GEMM (m201 template, plain-HIP reconstruction) for QKV
//     and scores: counted vmcnt(6) at phases 4/8, per-phase
//     {ds_read | stage-half | barrier | lgkmcnt(0) | setprio+16 MFMA | barrier}.
//     PV keeps the verified 128x128 2-phase kernel (better grid balance).
// ---------------------------------------------------------------------------

typedef __bf16 bf16x8 __attribute__((ext_vector_type(8)));
typedef float  f32x4  __attribute__((ext_vector_type(4)));

__device__ __forceinline__ void load_lds16(const __bf16* g, __bf16* l) {
    __builtin_amdgcn_global_load_lds(
        (const __attribute__((address_space(1))) void*)g,
        (__attribute__((address_space(3))) void*)l,
        16, 0, 0);
}

#define PH_MID() do {                                       \
    __builtin_amdgcn_sched_barrier(0);                      \
    __builtin_amdgcn_s_barrier();                           \
    asm volatile("s_waitcnt lgkmcnt(0)" ::: "memory");      \
    __builtin_amdgcn_sched_barrier(0);                      \
    __builtin_amdgcn_s_setprio(1);                          \
} while (0)

#define PH_END() do {                                       \
    __builtin_amdgcn_s_setprio(0);                          \
    __builtin_amdgcn_s_barrier();                           \
    __builtin_amdgcn_sched_barrier(0);                      \
} while (0)

#define PH_END_VM(cond) do {                                \
    __builtin_amdgcn_s_setprio(0);                          \
    if (cond) asm volatile("s_waitcnt vmcnt(6)" ::: "memory"); \
    else      asm volatile("s_waitcnt vmcnt(0)" ::: "memory"); \
    __builtin_amdgcn_s_barrier();                           \
    __builtin_amdgcn_sched_barrier(0);                      \
} while (0)

// ------------- merged fp32->bf16 converts + bias pack (1 launch) -----------
__global__ __launch_bounds__(256) void cvt_all(
        const float* __restrict__ x,
        const float* __restrict__ wq, const float* __restrict__ wk,
        const float* __restrict__ wv,
        const float* __restrict__ bq, const float* __restrict__ bk,
        const float* __restrict__ bv,
        __bf16* __restrict__ xb, __bf16* __restrict__ wb,
        float* __restrict__ bias3) {
    const long NX = 1048576, NW = 131072;
    long i = (long)blockIdx.x * 256 + threadIdx.x;
    const float* src; __bf16* dst; long c;
    if (i < NX) { src = x; dst = xb; c = i; }
    else if (i < NX + 3 * NW) {
        long j = i - NX;
        src = (j < NW) ? wq : (j < 2 * NW) ? wk : wv;
        c = j % NW;
        dst = wb + (j / NW) * (NW * 8);
    } else if (i < NX + 3 * NW + 384) {
        long cidx = i - (NX + 3 * NW);
        int seg = (int)(cidx >> 7);
        const float* bs = (seg == 0) ? bq : (seg == 1) ? bk : bv;
        long off = (cidx & 127) * 8;
        float4 a = *(const float4*)(bs + off);
        float4 b = *(const float4*)(bs + off + 4);
        *(float4*)(bias3 + cidx * 8)     = a;
        *(float4*)(bias3 + cidx * 8 + 4) = b;
        return;
    } else return;
    const float4* s4 = (const float4*)src;
    float4 a = s4[2 * c], b = s4[2 * c + 1];
    bf16x8 o;
    o[0] = (__bf16)a.x; o[1] = (__bf16)a.y; o[2] = (__bf16)a.z; o[3] = (__bf16)a.w;
    o[4] = (__bf16)b.x; o[5] = (__bf16)b.y; o[6] = (__bf16)b.z; o[7] = (__bf16)b.w;
    ((bf16x8*)dst)[c] = o;
}

// -------------- 256x256x64 8-phase NT GEMM: C = A * Bt^T -------------------
// 8 waves (2M x 4N), per-wave 128x64 = acc[8][4]. LDS: 2 x (A 16384 + B 16384)
// bf16 = 128 KiB. Half-tile = 128 rows x 64 cols = 16 KB, staged as 2
// global_load_lds/thread, XOR chunk-swizzle (pre-swizzled global source,
// linear LDS dest, swizzled ds_read_b128).
// Per K-tile: 4 phases, quadrants (iL,j01),(iH,j01),(iL,j23),(iH,j23);
// B reads all in phase 1, A-high reads in phase 2 => WAR-safe vs stage order
// {B0@p2, B1@p3, A0@p4, A1@p5(next group's p1 stages prev tile's A1)}.
// vmcnt(6) at phases 4/8 keeps 3 half-tiles in flight (2 loads each).
// MODE 0: fused QKV (n<2048 -> Q/K bf16 [m][n&1023]; n>=2048 -> V transposed)
// MODE 1: f32 = acc * scale (scores)
template <int MODE>
__global__ __launch_bounds__(512, 2) void gemm8p(
        const __bf16* __restrict__ A, const __bf16* __restrict__ Bt,
        void* __restrict__ C0, void* __restrict__ C1, void* __restrict__ C2,
        const float* __restrict__ bias,
        int lda, int ldb, int ldc, long sA, long sB, long sC,
        int K, float scale) {
    __shared__ __bf16 smem[65536];      // 2 x 32768 elems (A|B) = 128 KiB

    const int tid  = threadIdx.x;
    const int lane = tid & 63;
    const int wave = tid >> 6;
    const int mblk = blockIdx.y * 256;
    const int nblk = blockIdx.x * 256;
    const int z    = blockIdx.z;
    A  += (long)z * sA;
    Bt += (long)z * sB;

    const int wm   = (wave >> 2) * 128;   // 0 / 128
    const int wn   = (wave & 3) * 64;     // 0,64,128,192
    const int rsel = lane & 15;
    const int quad = lane >> 4;
    const int arow = wm + rsel;
    const int brow = wn + rsel;

    f32x4 zero = {0.f, 0.f, 0.f, 0.f};
    f32x4 acc[8][4];
#pragma unroll
    for (int i = 0; i < 8; ++i)
#pragma unroll
        for (int j = 0; j < 4; ++j) acc[i][j] = zero;

    // per-thread staging offsets (2 loads per half-tile)
    long offA[2], offB[2]; int loff[2];
#pragma unroll
    for (int it = 0; it < 2; ++it) {
        int s = it * 512 + tid;           // 0..1023 chunk index in half-tile
        int r = s >> 3, sl = s & 7;
        int cg = sl ^ (r & 7);            // pre-swizzled global chunk
        offA[it] = (long)(mblk + r) * lda + cg * 8;
        offB[it] = (long)(nblk + r) * ldb + cg * 8;
        loff[it] = s * 8;                 // linear LDS dest (elems)
    }

    auto stage_half = [&](int isB, int h, int t) {
        const __bf16* G = isB ? Bt : A;
        const int ld = isB ? ldb : lda;
        const long hoff = (long)h * 128 * ld;
        const long k0 = (long)t << 6;
        __bf16* dstb = smem + (t & 1) * 32768 + isB * 16384 + h * 8192;
#pragma unroll
        for (int it = 0; it < 2; ++it)
            load_lds16(G + (isB ? offB[it] : offA[it]) + hoff + k0,
                       dstb + loff[it]);
    };

    auto ld_frag = [&](const __bf16* base, int row, int q) -> bf16x8 {
        return *(const bf16x8*)&base[(row * 8 + (q ^ (row & 7))) * 8];
    };

    const int NT = K >> 6;

    // prologue: tile0 (B0,B1,A0,A1) + tile1 (B0,B1,A0); retire tile0
    stage_half(1, 0, 0); stage_half(1, 1, 0);
    stage_half(0, 0, 0); stage_half(0, 1, 0);
    stage_half(1, 0, 1); stage_half(1, 1, 1); stage_half(0, 0, 1);
    asm volatile("s_waitcnt vmcnt(6)" ::: "memory");
    __builtin_amdgcn_s_barrier();
    __builtin_amdgcn_sched_barrier(0);

    for (int tt = 0; tt < NT; tt += 2) {
#pragma unroll
        for (int sub = 0; sub < 2; ++sub) {
            const int t = tt + sub;               // t&1 == sub (tt even)
            const __bf16* lA = smem + sub * 32768;
            const __bf16* lB = lA + 16384;
            bf16x8 faL[4][2], faH[4][2], fb[4][2];

            // ---- phase 1: read all B + A-low; stage (t+1).A1 ----
#pragma unroll
            for (int j = 0; j < 4; ++j)
#pragma unroll
                for (int k = 0; k < 2; ++k)
                    fb[j][k] = ld_frag(lB, brow + j * 16, k * 4 + quad);
#pragma unroll
            for (int i = 0; i < 4; ++i)
#pragma unroll
                for (int k = 0; k < 2; ++k)
                    faL[i][k] = ld_frag(lA, arow + i * 16, k * 4 + quad);
            if (t + 1 < NT) stage_half(0, 1, t + 1);
            PH_MID();
#pragma unroll
            for (int i = 0; i < 4; ++i)
#pragma unroll
                for (int j = 0; j < 2; ++j)
#pragma unroll
                    for (int k = 0; k < 2; ++k)
                        acc[i][j] = __builtin_amdgcn_mfma_f32_16x16x32_bf16(
                            faL[i][k], fb[j][k], acc[i][j], 0, 0, 0);
            PH_END();

            // ---- phase 2: read A-high; stage (t+2).B0 ----
#pragma unroll
            for (int i = 0; i < 4; ++i)
#pragma unroll
                for (int k = 0; k < 2; ++k)
                    faH[i][k] = ld_frag(lA, arow + 64 + i * 16, k * 4 + quad);
            if (t + 2 < NT) stage_half(1, 0, t + 2);
            PH_MID();
#pragma unroll
            for (int i = 0; i < 4; ++i)
#pragma unroll
                for (int j = 0; j < 2; ++j)
#pragma unroll
                    for (int k = 0; k < 2; ++k)
                        acc[4 + i][j] = __builtin_amdgcn_mfma_f32_16x16x32_bf16(
                            faH[i][k], fb[j][k], acc[4 + i][j], 0, 0, 0);
            PH_END();

            // ---- phase 3: stage (t+2).B1 ----
            if (t + 2 < NT) stage_half(1, 1, t + 2);
            PH_MID();
#pragma unroll
            for (int i = 0; i < 4; ++i)
#pragma unroll
                for (int j = 0; j < 2; ++j)
#pragma unroll
                    for (int k = 0; k < 2; ++k)
                        acc[i][2 + j] = __builtin_amdgcn_mfma_f32_16x16x32_bf16(
                            faL[i][k], fb[2 + j][k], acc[i][2 + j], 0, 0, 0);
            PH_END();

            // ---- phase 4: stage (t+2).A0; counted vmcnt ----
            if (t + 2 < NT) stage_half(0, 0, t + 2);
            PH_MID();
#pragma unroll
            for (int i = 0; i < 4; ++i)
#pragma unroll
                for (int j = 0; j < 2; ++j)
#pragma unroll
                    for (int k = 0; k < 2; ++k)
                        acc[4 + i][2 + j] = __builtin_amdgcn_mfma_f32_16x16x32_bf16(
                            faH[i][k], fb[2 + j][k], acc[4 + i][2 + j], 0, 0, 0);
            PH_END_VM(t + 2 < NT);
        }
    }

    // epilogue: lane holds C[m = wm+i*16+quad*4+r][n = wn+j*16+rsel]
    const int rq = quad * 4;
    if constexpr (MODE == 0) {
        if (nblk >= 2048) {
            // ---- V path: transpose 256(t) x 256(h) tile via LDS ----
            __syncthreads();
            __bf16* tbuf = smem;     // [h_loc 0..255][32 chunks of 8], swizzled
#pragma unroll
            for (int i = 0; i < 8; ++i) {
#pragma unroll
                for (int j = 0; j < 4; ++j) {
                    const int n_loc = wn + j * 16 + rsel;        // h dim
                    const float bv = bias[nblk + n_loc];
                    const int m_loc = wm + i * 16 + rq;          // t dim (+r)
                    const int c  = m_loc >> 3;                   // 0..31
                    const int cs = c ^ (n_loc & 31);
                    __bf16* dst = &tbuf[n_loc * 256 + cs * 8 + (m_loc & 7)];
                    __bf16 tmp[4];
#pragma unroll
                    for (int r = 0; r < 4; ++r) tmp[r] = (__bf16)(acc[i][j][r] + bv);
                    *(uint64_t*)dst = *(const uint64_t*)tmp;
                }
            }
            __syncthreads();
            {
                const long b  = mblk >> 11;
                const long t0 = mblk & 2047;
                const long hbase = nblk - 2048;
                __bf16* vt = (__bf16*)C2 + b * (1024L * 2048) + t0;
#pragma unroll
                for (int pass = 0; pass < 16; ++pass) {
                    int h_loc = pass * 16 + (tid >> 5);          // 0..255
                    int c  = tid & 31;
                    int cs = c ^ (h_loc & 31);
                    bf16x8 vchunk = *(const bf16x8*)&tbuf[h_loc * 256 + cs * 8];
                    *(bf16x8*)(vt + (hbase + h_loc) * 2048 + c * 8) = vchunk;
                }
            }
        } else {
            // ---- Q/K path: [m][n&1023] bf16 store ----
#pragma unroll
            for (int i = 0; i < 8; ++i) {
#pragma unroll
                for (int j = 0; j < 4; ++j) {
                    const int n = nblk + wn + j * 16 + rsel;
                    __bf16* C = (n < 1024) ? (__bf16*)C0 : (__bf16*)C1;
                    const int col = n & 1023;
                    float bv = bias[n];
#pragma unroll
                    for (int r = 0; r < 4; ++r) {
                        int m = mblk + wm + i * 16 + rq + r;
                        C[(long)m * ldc + col] = (__bf16)(acc[i][j][r] + bv);
                    }
                }
            }
        }
    } else {
        float* C = (float*)C0 + (long)z * sC;
#pragma unroll
        for (int i = 0; i < 8; ++i) {
#pragma unroll
            for (int j = 0; j < 4; ++j) {
                const int n = nblk + wn + j * 16 + rsel;
#pragma unroll
                for (int r = 0; r < 4; ++r) {
                    int m = mblk + wm + i * 16 + rq + r;
                    C[(long)m * ldc + n] = acc[i][j][r] * scale;
                }
            }
        }
    }
}

// -------- PV: verified 128x128x64 2-phase kernel (f32 out, no scale) -------
__global__ __launch_bounds__(256, 4) void gemm_pv(
        const __bf16* __restrict__ A, const __bf16* __restrict__ Bt,
        float* __restrict__ C,
        int lda, int ldb, int ldc, long sA, long sB, long sC, int K) {
    __shared__ __bf16 smem[16384];
    __bf16* lA = smem;
    __bf16* lB = smem + 8192;

    const int tid  = threadIdx.x;
    const int lane = tid & 63;
    const int wave = tid >> 6;
    const int mblk = blockIdx.y * 128;
    const int nblk = blockIdx.x * 128;
    const int z    = blockIdx.z;
    A  += (long)z * sA;
    Bt += (long)z * sB;

    const int wm = (wave >> 1) * 64;
    const int wn = (wave & 1) * 64;

    f32x4 zero = {0.f, 0.f, 0.f, 0.f};
    f32x4 acc[4][4];
#pragma unroll
    for (int i = 0; i < 4; ++i)
#pragma unroll
        for (int j = 0; j < 4; ++j) acc[i][j] = zero;

    const int rsel = lane & 15;
    const int quad = lane >> 4;

    int srow[4], scol[4];
#pragma unroll
    for (int it = 0; it < 4; ++it) {
        int s  = tid + it * 256;
        srow[it] = s >> 3;
        scol[it] = ((s & 7) ^ (srow[it] & 7)) * 8;
    }

    for (int k0 = 0; k0 < K; k0 += 64) {
#pragma unroll
        for (int it = 0; it < 4; ++it) {
            int s = tid + it * 256;
            load_lds16(A  + (long)(mblk + srow[it]) * lda + k0 + scol[it], lA + s * 8);
            load_lds16(Bt + (long)(nblk + srow[it]) * ldb + k0 + scol[it], lB + s * 8);
        }
        __syncthreads();

#pragma unroll
        for (int half = 0; half < 2; ++half) {
            const int cq = quad + half * 4;
            bf16x8 fa[4], fbv[4];
#pragma unroll
            for (int i = 0; i < 4; ++i) {
                int ra = wm + i * 16 + rsel;
                fa[i] = *(const bf16x8*)&lA[(ra * 8 + (cq ^ (ra & 7))) * 8];
                int rb = wn + i * 16 + rsel;
                fbv[i] = *(const bf16x8*)&lB[(rb * 8 + (cq ^ (rb & 7))) * 8];
            }
#pragma unroll
            for (int i = 0; i < 4; ++i)
#pragma unroll
                for (int j = 0; j < 4; ++j)
                    acc[i][j] = __builtin_amdgcn_mfma_f32_16x16x32_bf16(
                        fa[i], fbv[j], acc[i][j], 0, 0, 0);
        }
        __syncthreads();
    }

    const int rq = quad * 4;
#pragma unroll
    for (int i = 0; i < 4; ++i) {
#pragma unroll
        for (int j = 0; j < 4; ++j) {
            const int n = nblk + wn + j * 16 + rsel;
            float* Cz = C + (long)z * sC;
#pragma unroll
            for (int r = 0; r < 4; ++r) {
                int m = mblk + wm + i * 16 + rq + r;
                Cz[(long)m * ldc + n] = acc[i][j][r];
            }
        }
    }
}

// ---------------- row softmax over 2048 floats, in-place + bf16 copy -------
__global__ __launch_bounds__(256) void softmax_rows(
        float* __restrict__ P, __bf16* __restrict__ Pb) {
    const long row = blockIdx.x;
    float*  p  = P  + row * 2048;
    __bf16* pb = Pb + row * 2048;
    const int tid  = threadIdx.x;
    const int lane = tid & 63;
    const int wave = tid >> 6;

    float4 v0 = ((const float4*)p)[tid * 2];
    float4 v1 = ((const float4*)p)[tid * 2 + 1];
    float e[8] = {v0.x, v0.y, v0.z, v0.w, v1.x, v1.y, v1.z, v1.w};

    float mx = e[0];
#pragma unroll
    for (int i = 1; i < 8; ++i) mx = fmaxf(mx, e[i]);
#pragma unroll
    for (int o = 1; o < 64; o <<= 1) mx = fmaxf(mx, __shfl_xor(mx, o, 64));

    __shared__ float redm[4], reds[4];
    if (lane == 0) redm[wave] = mx;
    __syncthreads();
    mx = fmaxf(fmaxf(redm[0], redm[1]), fmaxf(redm[2], redm[3]));

    float sum = 0.f;
#pragma unroll
    for (int i = 0; i < 8; ++i) { e[i] = __expf(e[i] - mx); sum += e[i]; }
#pragma unroll
    for (int o = 1; o < 64; o <<= 1) sum += __shfl_xor(sum, o, 64);
    if (lane == 0) reds[wave] = sum;
    __syncthreads();
    sum = reds[0] + reds[1] + reds[2] + reds[3];
    const float inv = 1.f / sum;

    float4 o0, o1;
    o0.x = e[0] * inv; o0.y = e[1] * inv; o0.z = e[2] * inv; o0.w = e[3] * inv;
    o1.x = e[4] * inv; o1.y = e[5] * inv; o1.z = e[6] * inv; o1.w = e[7] * inv;
    ((float4*)p)[tid * 2]     = o0;
    ((float4*)p)[tid * 2 + 1] = o1;
    bf16x8 ob;
    ob[0] = (__bf16)o0.x; ob[1] = (__bf16)o0.y; ob[2] = (__bf16)o0.z; ob[3] = (__bf16)o0.w;
    ob[4] = (__bf16)o1.x; ob[5] = (__bf16)o1.y; ob[6] = (__bf16)o1.z; ob[7] = (__bf16)o1.w;
    ((bf16x8*)pb)[tid] = ob;
}

// ---------------------------------------------------------------------------
extern "C" void kernel_launch(void* const* d_in, const int* in_sizes, int n_in,
                              void* d_out, int out_size, void* d_ws, size_t ws_size,
                              hipStream_t stream) {
    const float* x  = (const float*)d_in[0];
    const float* Wq = (const float*)d_in[1];
    const float* bq = (const float*)d_in[2];
    const float* Wk = (const float*)d_in[3];
    const float* bk = (const float*)d_in[4];
    const float* Wv = (const float*)d_in[5];
    const float* bv = (const float*)d_in[6];

    const int  S = 2048, H = 1024, I = 1024, B = 4;
    const long MS = (long)B * S;
    float* out_ws  = (float*)d_out;
    float* out_att = (float*)d_out + (long)B * S * H;

    char* w = (char*)d_ws;
    __bf16* x_bf   = (__bf16*)w; w += MS * I * 2;
    __bf16* wqkv   = (__bf16*)w; w += (long)3 * H * I * 2;
    float*  bias3  = (float*)w;  w += 4096 * 4;
    __bf16* q_bf   = (__bf16*)w; w += MS * H * 2;
    __bf16* k_bf   = (__bf16*)w; w += MS * H * 2;
    __bf16* vt_bf  = (__bf16*)w; w += MS * H * 2;
    __bf16* p_bf   = (__bf16*)w; w += (long)B * S * S * 2;

    // 1) all converts + bias pack
    {
        long tot = 1048576 + 3 * 131072 + 384;
        cvt_all<<<dim3((unsigned)((tot + 255) / 256)), dim3(256), 0, stream>>>(
            x, Wq, Wk, Wv, bq, bk, bv, x_bf, wqkv, bias3);
    }

    // 2) fused QKV projection (V pre-transposed): M=8192, N=3072, K=1024
    gemm8p<0><<<dim3(12, 32, 1), dim3(512), 0, stream>>>(
        x_bf, wqkv, q_bf, k_bf, vt_bf, bias3,
        1024, 1024, 1024, 0, 0, 0, 1024, 1.f);

    // 3) scores = Q K^T * 1/32 -> fp32 into attn-weights output region
    gemm8p<1><<<dim3(8, 8, 4), dim3(512), 0, stream>>>(
        q_bf, k_bf, out_att, nullptr, nullptr, nullptr,
        1024, 1024, 2048, (long)S * H, (long)S * H, (long)S * S, 1024, 0.03125f);

    // 4) softmax rows in-place (+ bf16 copy for PV)
    softmax_rows<<<dim3(8192), dim3(256), 0, stream>>>(out_att, p_bf);

    // 5) weighted_sum = P V : M=2048, N=1024, K=2048 per batch
    gemm_pv<<<dim3(8, 16, 4), dim3(256), 0, stream>>>(
        p_bf, vt_bf, out_ws,
        2048, 2048, 1024, (long)S * S, (long)S * H, (long)S * H, 2048);
}

// Round 3
// 307.899 us; speedup vs baseline: 1.0055x; 1.0052x over previous
//
#include <hip/hip_runtime.h>
#include <hip/hip_bf16.h>
#include <cstdint>

// ---------------------------------------------------------------------------
// SelfAttention: q,k,v = x@W{q,k,v}^T + b ; P = softmax(qk^T/sqrt(H)) ; out = P@v
// B=4, S=2048, H=I=1024. fp32 I/O, bf16 MFMA internally.
// R7: 256x256 8-phase GEMM v2 — balanced ds_reads (12/8/4/0 per phase),
//     quadrant order (iL,j01),(iH,j01),(iH,j23),(iL,j23) so P4 needs no reads,
//     WAR-safe stage slots {A1@P1, A0@P3, B0+B1@P4}, lgkmcnt(8) in P1,
//     vmcnt(6) at P4 only. QKV + scores use this; PV keeps verified 128².
// ---------------------------------------------------------------------------

typedef __bf16 bf16x8 __attribute__((ext_vector_type(8)));
typedef float  f32x4  __attribute__((ext_vector_type(4)));

__device__ __forceinline__ void load_lds16(const __bf16* g, __bf16* l) {
    __builtin_amdgcn_global_load_lds(
        (const __attribute__((address_space(1))) void*)g,
        (__attribute__((address_space(3))) void*)l,
        16, 0, 0);
}

#define PH_MID() do {                                       \
    __builtin_amdgcn_sched_barrier(0);                      \
    __builtin_amdgcn_s_barrier();                           \
    asm volatile("s_waitcnt lgkmcnt(0)" ::: "memory");      \
    __builtin_amdgcn_sched_barrier(0);                      \
    __builtin_amdgcn_s_setprio(1);                          \
} while (0)

#define PH_END() do {                                       \
    __builtin_amdgcn_s_setprio(0);                          \
    __builtin_amdgcn_s_barrier();                           \
    __builtin_amdgcn_sched_barrier(0);                      \
} while (0)

#define PH_END_VM(cond) do {                                \
    __builtin_amdgcn_s_setprio(0);                          \
    if (cond) asm volatile("s_waitcnt vmcnt(6)" ::: "memory"); \
    else      asm volatile("s_waitcnt vmcnt(0)" ::: "memory"); \
    __builtin_amdgcn_s_barrier();                           \
    __builtin_amdgcn_sched_barrier(0);                      \
} while (0)

// ------------- merged fp32->bf16 converts + bias pack (1 launch) -----------
__global__ __launch_bounds__(256) void cvt_all(
        const float* __restrict__ x,
        const float* __restrict__ wq, const float* __restrict__ wk,
        const float* __restrict__ wv,
        const float* __restrict__ bq, const float* __restrict__ bk,
        const float* __restrict__ bv,
        __bf16* __restrict__ xb, __bf16* __restrict__ wb,
        float* __restrict__ bias3) {
    const long NX = 1048576, NW = 131072;
    long i = (long)blockIdx.x * 256 + threadIdx.x;
    const float* src; __bf16* dst; long c;
    if (i < NX) { src = x; dst = xb; c = i; }
    else if (i < NX + 3 * NW) {
        long j = i - NX;
        src = (j < NW) ? wq : (j < 2 * NW) ? wk : wv;
        c = j % NW;
        dst = wb + (j / NW) * (NW * 8);
    } else if (i < NX + 3 * NW + 384) {
        long cidx = i - (NX + 3 * NW);
        int seg = (int)(cidx >> 7);
        const float* bs = (seg == 0) ? bq : (seg == 1) ? bk : bv;
        long off = (cidx & 127) * 8;
        float4 a = *(const float4*)(bs + off);
        float4 b = *(const float4*)(bs + off + 4);
        *(float4*)(bias3 + cidx * 8)     = a;
        *(float4*)(bias3 + cidx * 8 + 4) = b;
        return;
    } else return;
    const float4* s4 = (const float4*)src;
    float4 a = s4[2 * c], b = s4[2 * c + 1];
    bf16x8 o;
    o[0] = (__bf16)a.x; o[1] = (__bf16)a.y; o[2] = (__bf16)a.z; o[3] = (__bf16)a.w;
    o[4] = (__bf16)b.x; o[5] = (__bf16)b.y; o[6] = (__bf16)b.z; o[7] = (__bf16)b.w;
    ((bf16x8*)dst)[c] = o;
}

// -------------- 256x256x64 8-phase NT GEMM v2: C = A * Bt^T ----------------
// 8 waves (2M x 4N), per-wave 128x64 = acc[8][4]. LDS: 2 x (A 16384 + B 16384)
// bf16 = 128 KiB. Half-tile = 128 rows x 64 cols = 16 KB, 2 loads/thread,
// XOR chunk-swizzle (pre-swizzled global source, linear LDS dest).
// Per K-tile: P1 reads faL+fb01 (12), MFMA(iL,j01), stage (t+1).A1;
//             P2 reads faH (8),      MFMA(iH,j01);
//             P3 reads fb23 (4),     MFMA(iH,j23), stage (t+2).A0;
//             P4 no reads,           MFMA(iL,j23), stage (t+2).B0+B1, vmcnt(6).
// WAR: A0 reads end at P2 drain -> stage@P3 safe; B reads end at P3 drain
//      -> stage@P4 safe; A1 goes to the other buffer (read last tile) -> P1.
// vmcnt: 8 loads/tile; at P4-end 14 outstanding, vmcnt(6) retires tile t+1.
// MODE 0: fused QKV (n<2048 -> Q/K bf16 [m][n&1023]; n>=2048 -> V transposed)
// MODE 1: f32 = acc * scale (scores)
template <int MODE>
__global__ __launch_bounds__(512, 2) void gemm8p(
        const __bf16* __restrict__ A, const __bf16* __restrict__ Bt,
        void* __restrict__ C0, void* __restrict__ C1, void* __restrict__ C2,
        const float* __restrict__ bias,
        int lda, int ldb, int ldc, long sA, long sB, long sC,
        int K, float scale) {
    __shared__ __bf16 smem[65536];      // 2 x 32768 elems (A|B) = 128 KiB

    const int tid  = threadIdx.x;
    const int lane = tid & 63;
    const int wave = tid >> 6;
    const int mblk = blockIdx.y * 256;
    const int nblk = blockIdx.x * 256;
    const int z    = blockIdx.z;
    A  += (long)z * sA;
    Bt += (long)z * sB;

    const int wm   = (wave >> 2) * 128;   // 0 / 128
    const int wn   = (wave & 3) * 64;     // 0,64,128,192
    const int rsel = lane & 15;
    const int quad = lane >> 4;
    const int arow = wm + rsel;
    const int brow = wn + rsel;

    f32x4 zero = {0.f, 0.f, 0.f, 0.f};
    f32x4 acc[8][4];
#pragma unroll
    for (int i = 0; i < 8; ++i)
#pragma unroll
        for (int j = 0; j < 4; ++j) acc[i][j] = zero;

    // per-thread staging offsets (2 loads per half-tile)
    long offA[2], offB[2]; int loff[2];
#pragma unroll
    for (int it = 0; it < 2; ++it) {
        int s = it * 512 + tid;           // 0..1023 chunk index in half-tile
        int r = s >> 3, sl = s & 7;
        int cg = sl ^ (r & 7);            // pre-swizzled global chunk
        offA[it] = (long)(mblk + r) * lda + cg * 8;
        offB[it] = (long)(nblk + r) * ldb + cg * 8;
        loff[it] = s * 8;                 // linear LDS dest (elems)
    }

    auto stage_half = [&](int isB, int h, int t) {
        const __bf16* G = isB ? Bt : A;
        const int ld = isB ? ldb : lda;
        const long hoff = (long)h * 128 * ld;
        const long k0 = (long)t << 6;
        __bf16* dstb = smem + (t & 1) * 32768 + isB * 16384 + h * 8192;
#pragma unroll
        for (int it = 0; it < 2; ++it)
            load_lds16(G + (isB ? offB[it] : offA[it]) + hoff + k0,
                       dstb + loff[it]);
    };

    auto ld_frag = [&](const __bf16* base, int row, int q) -> bf16x8 {
        return *(const bf16x8*)&base[(row * 8 + (q ^ (row & 7))) * 8];
    };

    const int NT = K >> 6;

    // prologue: tile0 {A0,A1,B0,B1}, tile1 {A0,B0,B1}; tile1.A1 staged in P1 of t0
    stage_half(0, 0, 0); stage_half(0, 1, 0);
    stage_half(1, 0, 0); stage_half(1, 1, 0);
    stage_half(0, 0, 1); stage_half(1, 0, 1); stage_half(1, 1, 1);
    asm volatile("s_waitcnt vmcnt(6)" ::: "memory");
    __builtin_amdgcn_s_barrier();
    __builtin_amdgcn_sched_barrier(0);

    for (int tt = 0; tt < NT; tt += 2) {
#pragma unroll
        for (int sub = 0; sub < 2; ++sub) {
            const int t = tt + sub;               // t&1 == sub (tt even)
            const __bf16* lA = smem + sub * 32768;
            const __bf16* lB = lA + 16384;
            bf16x8 faL[4][2], faH[4][2], fb01[2][2], fb23[2][2];

            // ---- P1: read faL(8)+fb01(4); stage (t+1).A1; MFMA (iL,j01) ----
#pragma unroll
            for (int i = 0; i < 4; ++i)
#pragma unroll
                for (int k = 0; k < 2; ++k)
                    faL[i][k] = ld_frag(lA, arow + i * 16, k * 4 + quad);
#pragma unroll
            for (int j = 0; j < 2; ++j)
#pragma unroll
                for (int k = 0; k < 2; ++k)
                    fb01[j][k] = ld_frag(lB, brow + j * 16, k * 4 + quad);
            if (t + 1 < NT) stage_half(0, 1, t + 1);
            asm volatile("s_waitcnt lgkmcnt(8)" ::: "memory");
            PH_MID();
#pragma unroll
            for (int k = 0; k < 2; ++k)
#pragma unroll
                for (int i = 0; i < 4; ++i)
#pragma unroll
                    for (int j = 0; j < 2; ++j)
                        acc[i][j] = __builtin_amdgcn_mfma_f32_16x16x32_bf16(
                            faL[i][k], fb01[j][k], acc[i][j], 0, 0, 0);
            PH_END();

            // ---- P2: read faH(8); MFMA (iH,j01) ----
#pragma unroll
            for (int i = 0; i < 4; ++i)
#pragma unroll
                for (int k = 0; k < 2; ++k)
                    faH[i][k] = ld_frag(lA, arow + 64 + i * 16, k * 4 + quad);
            PH_MID();
#pragma unroll
            for (int k = 0; k < 2; ++k)
#pragma unroll
                for (int i = 0; i < 4; ++i)
#pragma unroll
                    for (int j = 0; j < 2; ++j)
                        acc[4 + i][j] = __builtin_amdgcn_mfma_f32_16x16x32_bf16(
                            faH[i][k], fb01[j][k], acc[4 + i][j], 0, 0, 0);
            PH_END();

            // ---- P3: read fb23(4); stage (t+2).A0; MFMA (iH,j23) ----
#pragma unroll
            for (int j = 0; j < 2; ++j)
#pragma unroll
                for (int k = 0; k < 2; ++k)
                    fb23[j][k] = ld_frag(lB, brow + 32 + j * 16, k * 4 + quad);
            if (t + 2 < NT) stage_half(0, 0, t + 2);
            PH_MID();
#pragma unroll
            for (int k = 0; k < 2; ++k)
#pragma unroll
                for (int i = 0; i < 4; ++i)
#pragma unroll
                    for (int j = 0; j < 2; ++j)
                        acc[4 + i][2 + j] = __builtin_amdgcn_mfma_f32_16x16x32_bf16(
                            faH[i][k], fb23[j][k], acc[4 + i][2 + j], 0, 0, 0);
            PH_END();

            // ---- P4: no reads; stage (t+2).B0+B1; MFMA (iL,j23); vmcnt ----
            if (t + 2 < NT) { stage_half(1, 0, t + 2); stage_half(1, 1, t + 2); }
            PH_MID();
#pragma unroll
            for (int k = 0; k < 2; ++k)
#pragma unroll
                for (int i = 0; i < 4; ++i)
#pragma unroll
                    for (int j = 0; j < 2; ++j)
                        acc[i][2 + j] = __builtin_amdgcn_mfma_f32_16x16x32_bf16(
                            faL[i][k], fb23[j][k], acc[i][2 + j], 0, 0, 0);
            PH_END_VM(t + 2 < NT);
        }
    }

    // epilogue: lane holds C[m = wm+i*16+quad*4+r][n = wn+j*16+rsel]
    const int rq = quad * 4;
    if constexpr (MODE == 0) {
        if (nblk >= 2048) {
            // ---- V path: transpose 256(t) x 256(h) tile via LDS ----
            __syncthreads();
            __bf16* tbuf = smem;     // [h_loc 0..255][32 chunks of 8], swizzled
#pragma unroll
            for (int i = 0; i < 8; ++i) {
#pragma unroll
                for (int j = 0; j < 4; ++j) {
                    const int n_loc = wn + j * 16 + rsel;        // h dim
                    const float bv = bias[nblk + n_loc];
                    const int m_loc = wm + i * 16 + rq;          // t dim (+r)
                    const int c  = m_loc >> 3;                   // 0..31
                    const int cs = c ^ (n_loc & 31);
                    __bf16* dst = &tbuf[n_loc * 256 + cs * 8 + (m_loc & 7)];
                    __bf16 tmp[4];
#pragma unroll
                    for (int r = 0; r < 4; ++r) tmp[r] = (__bf16)(acc[i][j][r] + bv);
                    *(uint64_t*)dst = *(const uint64_t*)tmp;
                }
            }
            __syncthreads();
            {
                const long b  = mblk >> 11;
                const long t0 = mblk & 2047;
                const long hbase = nblk - 2048;
                __bf16* vt = (__bf16*)C2 + b * (1024L * 2048) + t0;
#pragma unroll
                for (int pass = 0; pass < 16; ++pass) {
                    int h_loc = pass * 16 + (tid >> 5);          // 0..255
                    int c  = tid & 31;
                    int cs = c ^ (h_loc & 31);
                    bf16x8 vchunk = *(const bf16x8*)&tbuf[h_loc * 256 + cs * 8];
                    *(bf16x8*)(vt + (hbase + h_loc) * 2048 + c * 8) = vchunk;
                }
            }
        } else {
            // ---- Q/K path: [m][n&1023] bf16 store ----
#pragma unroll
            for (int i = 0; i < 8; ++i) {
#pragma unroll
                for (int j = 0; j < 4; ++j) {
                    const int n = nblk + wn + j * 16 + rsel;
                    __bf16* C = (n < 1024) ? (__bf16*)C0 : (__bf16*)C1;
                    const int col = n & 1023;
                    float bv = bias[n];
#pragma unroll
                    for (int r = 0; r < 4; ++r) {
                        int m = mblk + wm + i * 16 + rq + r;
                        C[(long)m * ldc + col] = (__bf16)(acc[i][j][r] + bv);
                    }
                }
            }
        }
    } else {
        float* C = (float*)C0 + (long)z * sC;
#pragma unroll
        for (int i = 0; i < 8; ++i) {
#pragma unroll
            for (int j = 0; j < 4; ++j) {
                const int n = nblk + wn + j * 16 + rsel;
#pragma unroll
                for (int r = 0; r < 4; ++r) {
                    int m = mblk + wm + i * 16 + rq + r;
                    C[(long)m * ldc + n] = acc[i][j][r] * scale;
                }
            }
        }
    }
}

// -------- PV: verified 128x128x64 2-phase kernel (f32 out, no scale) -------
__global__ __launch_bounds__(256, 4) void gemm_pv(
        const __bf16* __restrict__ A, const __bf16* __restrict__ Bt,
        float* __restrict__ C,
        int lda, int ldb, int ldc, long sA, long sB, long sC, int K) {
    __shared__ __bf16 smem[16384];
    __bf16* lA = smem;
    __bf16* lB = smem + 8192;

    const int tid  = threadIdx.x;
    const int lane = tid & 63;
    const int wave = tid >> 6;
    const int mblk = blockIdx.y * 128;
    const int nblk = blockIdx.x * 128;
    const int z    = blockIdx.z;
    A  += (long)z * sA;
    Bt += (long)z * sB;

    const int wm = (wave >> 1) * 64;
    const int wn = (wave & 1) * 64;

    f32x4 zero = {0.f, 0.f, 0.f, 0.f};
    f32x4 acc[4][4];
#pragma unroll
    for (int i = 0; i < 4; ++i)
#pragma unroll
        for (int j = 0; j < 4; ++j) acc[i][j] = zero;

    const int rsel = lane & 15;
    const int quad = lane >> 4;

    int srow[4], scol[4];
#pragma unroll
    for (int it = 0; it < 4; ++it) {
        int s  = tid + it * 256;
        srow[it] = s >> 3;
        scol[it] = ((s & 7) ^ (srow[it] & 7)) * 8;
    }

    for (int k0 = 0; k0 < K; k0 += 64) {
#pragma unroll
        for (int it = 0; it < 4; ++it) {
            int s = tid + it * 256;
            load_lds16(A  + (long)(mblk + srow[it]) * lda + k0 + scol[it], lA + s * 8);
            load_lds16(Bt + (long)(nblk + srow[it]) * ldb + k0 + scol[it], lB + s * 8);
        }
        __syncthreads();

#pragma unroll
        for (int half = 0; half < 2; ++half) {
            const int cq = quad + half * 4;
            bf16x8 fa[4], fbv[4];
#pragma unroll
            for (int i = 0; i < 4; ++i) {
                int ra = wm + i * 16 + rsel;
                fa[i] = *(const bf16x8*)&lA[(ra * 8 + (cq ^ (ra & 7))) * 8];
                int rb = wn + i * 16 + rsel;
                fbv[i] = *(const bf16x8*)&lB[(rb * 8 + (cq ^ (rb & 7))) * 8];
            }
#pragma unroll
            for (int i = 0; i < 4; ++i)
#pragma unroll
                for (int j = 0; j < 4; ++j)
                    acc[i][j] = __builtin_amdgcn_mfma_f32_16x16x32_bf16(
                        fa[i], fbv[j], acc[i][j], 0, 0, 0);
        }
        __syncthreads();
    }

    const int rq = quad * 4;
#pragma unroll
    for (int i = 0; i < 4; ++i) {
#pragma unroll
        for (int j = 0; j < 4; ++j) {
            const int n = nblk + wn + j * 16 + rsel;
            float* Cz = C + (long)z * sC;
#pragma unroll
            for (int r = 0; r < 4; ++r) {
                int m = mblk + wm + i * 16 + rq + r;
                Cz[(long)m * ldc + n] = acc[i][j][r];
            }
        }
    }
}

// ---------------- row softmax over 2048 floats, in-place + bf16 copy -------
__global__ __launch_bounds__(256) void softmax_rows(
        float* __restrict__ P, __bf16* __restrict__ Pb) {
    const long row = blockIdx.x;
    float*  p  = P  + row * 2048;
    __bf16* pb = Pb + row * 2048;
    const int tid  = threadIdx.x;
    const int lane = tid & 63;
    const int wave = tid >> 6;

    float4 v0 = ((const float4*)p)[tid * 2];
    float4 v1 = ((const float4*)p)[tid * 2 + 1];
    float e[8] = {v0.x, v0.y, v0.z, v0.w, v1.x, v1.y, v1.z, v1.w};

    float mx = e[0];
#pragma unroll
    for (int i = 1; i < 8; ++i) mx = fmaxf(mx, e[i]);
#pragma unroll
    for (int o = 1; o < 64; o <<= 1) mx = fmaxf(mx, __shfl_xor(mx, o, 64));

    __shared__ float redm[4], reds[4];
    if (lane == 0) redm[wave] = mx;
    __syncthreads();
    mx = fmaxf(fmaxf(redm[0], redm[1]), fmaxf(redm[2], redm[3]));

    float sum = 0.f;
#pragma unroll
    for (int i = 0; i < 8; ++i) { e[i] = __expf(e[i] - mx); sum += e[i]; }
#pragma unroll
    for (int o = 1; o < 64; o <<= 1) sum += __shfl_xor(sum, o, 64);
    if (lane == 0) reds[wave] = sum;
    __syncthreads();
    sum = reds[0] + reds[1] + reds[2] + reds[3];
    const float inv = 1.f / sum;

    float4 o0, o1;
    o0.x = e[0] * inv; o0.y = e[1] * inv; o0.z = e[2] * inv; o0.w = e[3] * inv;
    o1.x = e[4] * inv; o1.y = e[5] * inv; o1.z = e[6] * inv; o1.w = e[7] * inv;
    ((float4*)p)[tid * 2]     = o0;
    ((float4*)p)[tid * 2 + 1] = o1;
    bf16x8 ob;
    ob[0] = (__bf16)o0.x; ob[1] = (__bf16)o0.y; ob[2] = (__bf16)o0.z; ob[3] = (__bf16)o0.w;
    ob[4] = (__bf16)o1.x; ob[5] = (__bf16)o1.y; ob[6] = (__bf16)o1.z; ob[7] = (__bf16)o1.w;
    ((bf16x8*)pb)[tid] = ob;
}

// ---------------------------------------------------------------------------
extern "C" void kernel_launch(void* const* d_in, const int* in_sizes, int n_in,
                              void* d_out, int out_size, void* d_ws, size_t ws_size,
                              hipStream_t stream) {
    const float* x  = (const float*)d_in[0];
    const float* Wq = (const float*)d_in[1];
    const float* bq = (const float*)d_in[2];
    const float* Wk = (const float*)d_in[3];
    const float* bk = (const float*)d_in[4];
    const float* Wv = (const float*)d_in[5];
    const float* bv = (const float*)d_in[6];

    const int  S = 2048, H = 1024, I = 1024, B = 4;
    const long MS = (long)B * S;
    float* out_ws  = (float*)d_out;
    float* out_att = (float*)d_out + (long)B * S * H;

    char* w = (char*)d_ws;
    __bf16* x_bf   = (__bf16*)w; w += MS * I * 2;
    __bf16* wqkv   = (__bf16*)w; w += (long)3 * H * I * 2;
    float*  bias3  = (float*)w;  w += 4096 * 4;
    __bf16* q_bf   = (__bf16*)w; w += MS * H * 2;
    __bf16* k_bf   = (__bf16*)w; w += MS * H * 2;
    __bf16* vt_bf  = (__bf16*)w; w += MS * H * 2;
    __bf16* p_bf   = (__bf16*)w; w += (long)B * S * S * 2;

    // 1) all converts + bias pack
    {
        long tot = 1048576 + 3 * 131072 + 384;
        cvt_all<<<dim3((unsigned)((tot + 255) / 256)), dim3(256), 0, stream>>>(
            x, Wq, Wk, Wv, bq, bk, bv, x_bf, wqkv, bias3);
    }

    // 2) fused QKV projection (V pre-transposed): M=8192, N=3072, K=1024
    gemm8p<0><<<dim3(12, 32, 1), dim3(512), 0, stream>>>(
        x_bf, wqkv, q_bf, k_bf, vt_bf, bias3,
        1024, 1024, 1024, 0, 0, 0, 1024, 1.f);

    // 3) scores = Q K^T * 1/32 -> fp32 into attn-weights output region
    gemm8p<1><<<dim3(8, 8, 4), dim3(512), 0, stream>>>(
        q_bf, k_bf, out_att, nullptr, nullptr, nullptr,
        1024, 1024, 2048, (long)S * H, (long)S * H, (long)S * S, 1024, 0.03125f);

    // 4) softmax rows in-place (+ bf16 copy for PV)
    softmax_rows<<<dim3(8192), dim3(256), 0, stream>>>(out_att, p_bf);

    // 5) weighted_sum = P V : M=2048, N=1024, K=2048 per batch
    gemm_pv<<<dim3(8, 16, 4), dim3(256), 0, stream>>>(
        p_bf, vt_bf, out_ws,
        2048, 2048, 1024, (long)S * S, (long)S * H, (long)S * H, 2048);
}

// Round 5
// 305.878 us; speedup vs baseline: 1.0121x; 1.0066x over previous
//
#include <hip/hip_runtime.h>
#include <hip/hip_bf16.h>
#include <cstdint>

// ---------------------------------------------------------------------------
// SelfAttention: q,k,v = x@W{q,k,v}^T + b ; P = softmax(qk^T/sqrt(H)) ; out = P@v
// B=4, S=2048, H=I=1024. fp32 I/O, bf16 MFMA internally (tol 6.25e-3).
// R9: revert to the verified R4 structure (299 µs). The 8-phase arc (R5-R8)
//     is closed: coarse pipeline regressed (m196-class), two balanced 8-phase
//     variants were null at MfmaUtil 27% (core ~930 TF = m97 ceiling), and the
//     short-live-range variant broke correctness. R4's components each sit at
//     their verified local ceilings: QKV 873 TF (m97-structure ceiling),
//     softmax ~88% HBM BW, PV/scores same structure. Remaining catalog levers
//     (T1/T5/T19) predict null-to-negative in this regime (L3-fit operands,
//     lockstep 2-phase waves, graft-null).
// ---------------------------------------------------------------------------

typedef __bf16 bf16x8 __attribute__((ext_vector_type(8)));
typedef float  f32x4  __attribute__((ext_vector_type(4)));

__device__ __forceinline__ void load_lds16(const __bf16* g, __bf16* l) {
    __builtin_amdgcn_global_load_lds(
        (const __attribute__((address_space(1))) void*)g,
        (__attribute__((address_space(3))) void*)l,
        16, 0, 0);
}

// ------------- merged fp32->bf16 converts + bias pack (1 launch) -----------
__global__ __launch_bounds__(256) void cvt_all(
        const float* __restrict__ x,
        const float* __restrict__ wq, const float* __restrict__ wk,
        const float* __restrict__ wv,
        const float* __restrict__ bq, const float* __restrict__ bk,
        const float* __restrict__ bv,
        __bf16* __restrict__ xb, __bf16* __restrict__ wb,
        float* __restrict__ bias3) {
    const long NX = 1048576, NW = 131072;
    long i = (long)blockIdx.x * 256 + threadIdx.x;
    const float* src; __bf16* dst; long c;
    if (i < NX) { src = x; dst = xb; c = i; }
    else if (i < NX + 3 * NW) {
        long j = i - NX;
        src = (j < NW) ? wq : (j < 2 * NW) ? wk : wv;
        c = j % NW;
        dst = wb + (j / NW) * (NW * 8);
    } else if (i < NX + 3 * NW + 384) {
        long cidx = i - (NX + 3 * NW);
        int seg = (int)(cidx >> 7);
        const float* bs = (seg == 0) ? bq : (seg == 1) ? bk : bv;
        long off = (cidx & 127) * 8;
        float4 a = *(const float4*)(bs + off);
        float4 b = *(const float4*)(bs + off + 4);
        *(float4*)(bias3 + cidx * 8)     = a;
        *(float4*)(bias3 + cidx * 8 + 4) = b;
        return;
    } else return;
    const float4* s4 = (const float4*)src;
    float4 a = s4[2 * c], b = s4[2 * c + 1];
    bf16x8 o;
    o[0] = (__bf16)a.x; o[1] = (__bf16)a.y; o[2] = (__bf16)a.z; o[3] = (__bf16)a.w;
    o[4] = (__bf16)b.x; o[5] = (__bf16)b.y; o[6] = (__bf16)b.z; o[7] = (__bf16)b.w;
    ((bf16x8*)dst)[c] = o;
}

// ---------------- NT bf16 GEMM: C[m,n] = sum_k A[m,k] * Bt[n,k] ------------
// 128x128 tile, BK=64, 4 waves (2x2 of 64x64), 16x16x32 MFMA, 4x4 frags/wave.
// LDS: 16B chunks, chunk (row,cs) holds cg = cs ^ (row&7).  Zero conflicts.
// MODE 0: fused QKV. n<2048 -> bf16=acc+bias to C0/C1 [m][n&1023];
//         n>=2048 -> V: LDS-transposed, written as vt[h][t] to C2.
// MODE 1: f32 = acc * scale  (scores)
// MODE 2: f32 = acc          (PV)
template <int MODE>
__global__ __launch_bounds__(256, 4) void gemm_nt(
        const __bf16* __restrict__ A, const __bf16* __restrict__ Bt,
        void* __restrict__ C0, void* __restrict__ C1, void* __restrict__ C2,
        const float* __restrict__ bias,
        int lda, int ldb, int ldc, long sA, long sB, long sC,
        int K, float scale) {
    __shared__ __bf16 smem[16384];      // lA | lB, reused as transpose buffer
    __bf16* lA = smem;
    __bf16* lB = smem + 8192;

    const int tid  = threadIdx.x;
    const int lane = tid & 63;
    const int wave = tid >> 6;
    const int mblk = blockIdx.y * 128;
    const int nblk = blockIdx.x * 128;
    const int z    = blockIdx.z;
    A  += (long)z * sA;
    Bt += (long)z * sB;

    const int wm = (wave >> 1) * 64;
    const int wn = (wave & 1) * 64;

    f32x4 zero = {0.f, 0.f, 0.f, 0.f};
    f32x4 acc[4][4];
#pragma unroll
    for (int i = 0; i < 4; ++i)
#pragma unroll
        for (int j = 0; j < 4; ++j) acc[i][j] = zero;

    const int rsel = lane & 15;
    const int quad = lane >> 4;

    int srow[4], scol[4];
#pragma unroll
    for (int it = 0; it < 4; ++it) {
        int s  = tid + it * 256;
        srow[it] = s >> 3;
        scol[it] = ((s & 7) ^ (srow[it] & 7)) * 8;
    }

    for (int k0 = 0; k0 < K; k0 += 64) {
#pragma unroll
        for (int it = 0; it < 4; ++it) {
            int s = tid + it * 256;
            load_lds16(A  + (long)(mblk + srow[it]) * lda + k0 + scol[it], lA + s * 8);
            load_lds16(Bt + (long)(nblk + srow[it]) * ldb + k0 + scol[it], lB + s * 8);
        }
        __syncthreads();

#pragma unroll
        for (int half = 0; half < 2; ++half) {
            const int cq = quad + half * 4;
            bf16x8 fa[4], fb[4];
#pragma unroll
            for (int i = 0; i < 4; ++i) {
                int ra = wm + i * 16 + rsel;
                fa[i] = *(const bf16x8*)&lA[(ra * 8 + (cq ^ (ra & 7))) * 8];
                int rb = wn + i * 16 + rsel;
                fb[i] = *(const bf16x8*)&lB[(rb * 8 + (cq ^ (rb & 7))) * 8];
            }
#pragma unroll
            for (int i = 0; i < 4; ++i)
#pragma unroll
                for (int j = 0; j < 4; ++j)
                    acc[i][j] = __builtin_amdgcn_mfma_f32_16x16x32_bf16(
                        fa[i], fb[j], acc[i][j], 0, 0, 0);
        }
        __syncthreads();
    }

    // epilogue: lane holds C[m = wm+i*16+quad*4+r][n = wn+j*16+rsel]
    const int rq = quad * 4;
    if constexpr (MODE == 0) {
        if (nblk >= 2048) {
            // ---- V path: transpose tile via LDS, store vt[h][t] ----
            // tbuf element (n_loc, m_loc) at n_loc*128 + (chunk^ (n_loc&15))*8
            // + (m_loc&7).  Writes: b64 per (i,j); reads: b128 per chunk.
            __bf16* tbuf = smem;
#pragma unroll
            for (int i = 0; i < 4; ++i) {
#pragma unroll
                for (int j = 0; j < 4; ++j) {
                    const int n_loc = wn + j * 16 + rsel;
                    const float bv = bias[nblk + n_loc];
                    const int m_loc = wm + i * 16 + rq;       // +r, r=0..3
                    const int c  = m_loc >> 3;
                    const int cs = c ^ (n_loc & 15);
                    __bf16* dst = &tbuf[n_loc * 128 + cs * 8 + (m_loc & 7)];
                    __bf16 tmp[4];
#pragma unroll
                    for (int r = 0; r < 4; ++r) tmp[r] = (__bf16)(acc[i][j][r] + bv);
                    *(uint64_t*)dst = *(const uint64_t*)tmp;
                }
            }
            __syncthreads();
            // store: thread t -> row n_loc = t&127, chunk half cpart = t>>7
            {
                __bf16* vt = (__bf16*)C2;
                const int n_loc = tid & 127;
                const int cpart = tid >> 7;
                const long b = mblk >> 11;                    // batch
                const long t0 = mblk & 2047;
                const long h  = nblk - 2048 + n_loc;
                __bf16* gdst = vt + b * (1024L * 2048) + h * 2048 + t0;
#pragma unroll
                for (int s = 0; s < 8; ++s) {
                    int c  = cpart * 8 + s;
                    int cs = c ^ (n_loc & 15);
                    bf16x8 vchunk = *(const bf16x8*)&tbuf[n_loc * 128 + cs * 8];
                    *(bf16x8*)(gdst + c * 8) = vchunk;
                }
            }
        } else {
            // ---- Q/K path: normal [m][n] bf16 store ----
#pragma unroll
            for (int i = 0; i < 4; ++i) {
#pragma unroll
                for (int j = 0; j < 4; ++j) {
                    const int n = nblk + wn + j * 16 + rsel;
                    __bf16* C = (n < 1024) ? (__bf16*)C0 : (__bf16*)C1;
                    const int col = n & 1023;
                    float bv = bias[n];
#pragma unroll
                    for (int r = 0; r < 4; ++r) {
                        int m = mblk + wm + i * 16 + rq + r;
                        C[(long)m * ldc + col] = (__bf16)(acc[i][j][r] + bv);
                    }
                }
            }
        }
    } else {
#pragma unroll
        for (int i = 0; i < 4; ++i) {
#pragma unroll
            for (int j = 0; j < 4; ++j) {
                const int n = nblk + wn + j * 16 + rsel;
                float* C = (float*)C0 + (long)z * sC;
                if constexpr (MODE == 1) {
#pragma unroll
                    for (int r = 0; r < 4; ++r) {
                        int m = mblk + wm + i * 16 + rq + r;
                        C[(long)m * ldc + n] = acc[i][j][r] * scale;
                    }
                } else {
#pragma unroll
                    for (int r = 0; r < 4; ++r) {
                        int m = mblk + wm + i * 16 + rq + r;
                        C[(long)m * ldc + n] = acc[i][j][r];
                    }
                }
            }
        }
    }
}

// ---------------- row softmax over 2048 floats, in-place + bf16 copy -------
__global__ __launch_bounds__(256) void softmax_rows(
        float* __restrict__ P, __bf16* __restrict__ Pb) {
    const long row = blockIdx.x;
    float*  p  = P  + row * 2048;
    __bf16* pb = Pb + row * 2048;
    const int tid  = threadIdx.x;
    const int lane = tid & 63;
    const int wave = tid >> 6;

    float4 v0 = ((const float4*)p)[tid * 2];
    float4 v1 = ((const float4*)p)[tid * 2 + 1];
    float e[8] = {v0.x, v0.y, v0.z, v0.w, v1.x, v1.y, v1.z, v1.w};

    float mx = e[0];
#pragma unroll
    for (int i = 1; i < 8; ++i) mx = fmaxf(mx, e[i]);
#pragma unroll
    for (int o = 1; o < 64; o <<= 1) mx = fmaxf(mx, __shfl_xor(mx, o, 64));

    __shared__ float redm[4], reds[4];
    if (lane == 0) redm[wave] = mx;
    __syncthreads();
    mx = fmaxf(fmaxf(redm[0], redm[1]), fmaxf(redm[2], redm[3]));

    float sum = 0.f;
#pragma unroll
    for (int i = 0; i < 8; ++i) { e[i] = __expf(e[i] - mx); sum += e[i]; }
#pragma unroll
    for (int o = 1; o < 64; o <<= 1) sum += __shfl_xor(sum, o, 64);
    if (lane == 0) reds[wave] = sum;
    __syncthreads();
    sum = reds[0] + reds[1] + reds[2] + reds[3];
    const float inv = 1.f / sum;

    float4 o0, o1;
    o0.x = e[0] * inv; o0.y = e[1] * inv; o0.z = e[2] * inv; o0.w = e[3] * inv;
    o1.x = e[4] * inv; o1.y = e[5] * inv; o1.z = e[6] * inv; o1.w = e[7] * inv;
    ((float4*)p)[tid * 2]     = o0;
    ((float4*)p)[tid * 2 + 1] = o1;
    bf16x8 ob;
    ob[0] = (__bf16)o0.x; ob[1] = (__bf16)o0.y; ob[2] = (__bf16)o0.z; ob[3] = (__bf16)o0.w;
    ob[4] = (__bf16)o1.x; ob[5] = (__bf16)o1.y; ob[6] = (__bf16)o1.z; ob[7] = (__bf16)o1.w;
    ((bf16x8*)pb)[tid] = ob;
}

// ---------------------------------------------------------------------------
extern "C" void kernel_launch(void* const* d_in, const int* in_sizes, int n_in,
                              void* d_out, int out_size, void* d_ws, size_t ws_size,
                              hipStream_t stream) {
    const float* x  = (const float*)d_in[0];
    const float* Wq = (const float*)d_in[1];
    const float* bq = (const float*)d_in[2];
    const float* Wk = (const float*)d_in[3];
    const float* bk = (const float*)d_in[4];
    const float* Wv = (const float*)d_in[5];
    const float* bv = (const float*)d_in[6];

    const int  S = 2048, H = 1024, I = 1024, B = 4;
    const long MS = (long)B * S;
    float* out_ws  = (float*)d_out;
    float* out_att = (float*)d_out + (long)B * S * H;

    char* w = (char*)d_ws;
    __bf16* x_bf   = (__bf16*)w; w += MS * I * 2;
    __bf16* wqkv   = (__bf16*)w; w += (long)3 * H * I * 2;
    float*  bias3  = (float*)w;  w += 4096 * 4;
    __bf16* q_bf   = (__bf16*)w; w += MS * H * 2;
    __bf16* k_bf   = (__bf16*)w; w += MS * H * 2;
    __bf16* vt_bf  = (__bf16*)w; w += MS * H * 2;
    __bf16* p_bf   = (__bf16*)w; w += (long)B * S * S * 2;

    // 1) all converts + bias pack
    {
        long tot = 1048576 + 3 * 131072 + 384;
        cvt_all<<<dim3((unsigned)((tot + 255) / 256)), dim3(256), 0, stream>>>(
            x, Wq, Wk, Wv, bq, bk, bv, x_bf, wqkv, bias3);
    }

    // 2) fused QKV projection (V written pre-transposed): M=8192, N=3072, K=1024
    gemm_nt<0><<<dim3(24, 64, 1), dim3(256), 0, stream>>>(
        x_bf, wqkv, q_bf, k_bf, vt_bf, bias3,
        1024, 1024, 1024, 0, 0, 0, 1024, 1.f);

    // 3) scores = Q K^T * 1/32 -> fp32 into attn-weights output region
    gemm_nt<1><<<dim3(16, 16, 4), dim3(256), 0, stream>>>(
        q_bf, k_bf, out_att, nullptr, nullptr, nullptr,
        1024, 1024, 2048, (long)S * H, (long)S * H, (long)S * S, 1024, 0.03125f);

    // 4) softmax rows in-place (+ bf16 copy for PV)
    softmax_rows<<<dim3(8192), dim3(256), 0, stream>>>(out_att, p_bf);

    // 5) weighted_sum = P V : M=2048, N=1024, K=2048 per batch
    gemm_nt<2><<<dim3(8, 16, 4), dim3(256), 0, stream>>>(
        p_bf, vt_bf, out_ws, nullptr, nullptr, nullptr,
        2048, 2048, 1024, (long)S * S, (long)S * H, (long)S * H, 2048, 1.f);
}

// Round 6
// 296.622 us; speedup vs baseline: 1.0437x; 1.0312x over previous
//
#include <hip/hip_runtime.h>
#include <hip/hip_bf16.h>
#include <cstdint>

// ---------------------------------------------------------------------------
// SelfAttention: q,k,v = x@W{q,k,v}^T + b ; P = softmax(qk^T/sqrt(H)) ; out = P@v
// B=4, S=2048, H=I=1024. fp32 I/O, bf16 MFMA internally (tol 6.25e-3).
// R10: R9 (verified 299-306 µs structure) + bf16 scores hand-off:
//      scores GEMM (MODE 1) writes bf16 directly into p_bf (33.5 MB instead
//      of 67 MB f32); softmax reads bf16 scores, writes f32 normalized P to
//      out_att + normalized bf16 back in-place to p_bf for PV.
//      -67 MB HBM round-trip; score precision already bf16-input-limited
//      (~0.003), binding absmax is PV accumulation (untouched).
// ---------------------------------------------------------------------------

typedef __bf16 bf16x8 __attribute__((ext_vector_type(8)));
typedef float  f32x4  __attribute__((ext_vector_type(4)));

__device__ __forceinline__ void load_lds16(const __bf16* g, __bf16* l) {
    __builtin_amdgcn_global_load_lds(
        (const __attribute__((address_space(1))) void*)g,
        (__attribute__((address_space(3))) void*)l,
        16, 0, 0);
}

// ------------- merged fp32->bf16 converts + bias pack (1 launch) -----------
__global__ __launch_bounds__(256) void cvt_all(
        const float* __restrict__ x,
        const float* __restrict__ wq, const float* __restrict__ wk,
        const float* __restrict__ wv,
        const float* __restrict__ bq, const float* __restrict__ bk,
        const float* __restrict__ bv,
        __bf16* __restrict__ xb, __bf16* __restrict__ wb,
        float* __restrict__ bias3) {
    const long NX = 1048576, NW = 131072;
    long i = (long)blockIdx.x * 256 + threadIdx.x;
    const float* src; __bf16* dst; long c;
    if (i < NX) { src = x; dst = xb; c = i; }
    else if (i < NX + 3 * NW) {
        long j = i - NX;
        src = (j < NW) ? wq : (j < 2 * NW) ? wk : wv;
        c = j % NW;
        dst = wb + (j / NW) * (NW * 8);
    } else if (i < NX + 3 * NW + 384) {
        long cidx = i - (NX + 3 * NW);
        int seg = (int)(cidx >> 7);
        const float* bs = (seg == 0) ? bq : (seg == 1) ? bk : bv;
        long off = (cidx & 127) * 8;
        float4 a = *(const float4*)(bs + off);
        float4 b = *(const float4*)(bs + off + 4);
        *(float4*)(bias3 + cidx * 8)     = a;
        *(float4*)(bias3 + cidx * 8 + 4) = b;
        return;
    } else return;
    const float4* s4 = (const float4*)src;
    float4 a = s4[2 * c], b = s4[2 * c + 1];
    bf16x8 o;
    o[0] = (__bf16)a.x; o[1] = (__bf16)a.y; o[2] = (__bf16)a.z; o[3] = (__bf16)a.w;
    o[4] = (__bf16)b.x; o[5] = (__bf16)b.y; o[6] = (__bf16)b.z; o[7] = (__bf16)b.w;
    ((bf16x8*)dst)[c] = o;
}

// ---------------- NT bf16 GEMM: C[m,n] = sum_k A[m,k] * Bt[n,k] ------------
// 128x128 tile, BK=64, 4 waves (2x2 of 64x64), 16x16x32 MFMA, 4x4 frags/wave.
// LDS: 16B chunks, chunk (row,cs) holds cg = cs ^ (row&7).  Zero conflicts.
// MODE 0: fused QKV. n<2048 -> bf16=acc+bias to C0/C1 [m][n&1023];
//         n>=2048 -> V: LDS-transposed, written as vt[h][t] to C2.
// MODE 1: bf16 = acc * scale  (scores, written to p_bf workspace)
// MODE 2: f32 = acc           (PV)
template <int MODE>
__global__ __launch_bounds__(256, 4) void gemm_nt(
        const __bf16* __restrict__ A, const __bf16* __restrict__ Bt,
        void* __restrict__ C0, void* __restrict__ C1, void* __restrict__ C2,
        const float* __restrict__ bias,
        int lda, int ldb, int ldc, long sA, long sB, long sC,
        int K, float scale) {
    __shared__ __bf16 smem[16384];      // lA | lB, reused as transpose buffer
    __bf16* lA = smem;
    __bf16* lB = smem + 8192;

    const int tid  = threadIdx.x;
    const int lane = tid & 63;
    const int wave = tid >> 6;
    const int mblk = blockIdx.y * 128;
    const int nblk = blockIdx.x * 128;
    const int z    = blockIdx.z;
    A  += (long)z * sA;
    Bt += (long)z * sB;

    const int wm = (wave >> 1) * 64;
    const int wn = (wave & 1) * 64;

    f32x4 zero = {0.f, 0.f, 0.f, 0.f};
    f32x4 acc[4][4];
#pragma unroll
    for (int i = 0; i < 4; ++i)
#pragma unroll
        for (int j = 0; j < 4; ++j) acc[i][j] = zero;

    const int rsel = lane & 15;
    const int quad = lane >> 4;

    int srow[4], scol[4];
#pragma unroll
    for (int it = 0; it < 4; ++it) {
        int s  = tid + it * 256;
        srow[it] = s >> 3;
        scol[it] = ((s & 7) ^ (srow[it] & 7)) * 8;
    }

    for (int k0 = 0; k0 < K; k0 += 64) {
#pragma unroll
        for (int it = 0; it < 4; ++it) {
            int s = tid + it * 256;
            load_lds16(A  + (long)(mblk + srow[it]) * lda + k0 + scol[it], lA + s * 8);
            load_lds16(Bt + (long)(nblk + srow[it]) * ldb + k0 + scol[it], lB + s * 8);
        }
        __syncthreads();

#pragma unroll
        for (int half = 0; half < 2; ++half) {
            const int cq = quad + half * 4;
            bf16x8 fa[4], fb[4];
#pragma unroll
            for (int i = 0; i < 4; ++i) {
                int ra = wm + i * 16 + rsel;
                fa[i] = *(const bf16x8*)&lA[(ra * 8 + (cq ^ (ra & 7))) * 8];
                int rb = wn + i * 16 + rsel;
                fb[i] = *(const bf16x8*)&lB[(rb * 8 + (cq ^ (rb & 7))) * 8];
            }
#pragma unroll
            for (int i = 0; i < 4; ++i)
#pragma unroll
                for (int j = 0; j < 4; ++j)
                    acc[i][j] = __builtin_amdgcn_mfma_f32_16x16x32_bf16(
                        fa[i], fb[j], acc[i][j], 0, 0, 0);
        }
        __syncthreads();
    }

    // epilogue: lane holds C[m = wm+i*16+quad*4+r][n = wn+j*16+rsel]
    const int rq = quad * 4;
    if constexpr (MODE == 0) {
        if (nblk >= 2048) {
            // ---- V path: transpose tile via LDS, store vt[h][t] ----
            __bf16* tbuf = smem;
#pragma unroll
            for (int i = 0; i < 4; ++i) {
#pragma unroll
                for (int j = 0; j < 4; ++j) {
                    const int n_loc = wn + j * 16 + rsel;
                    const float bv = bias[nblk + n_loc];
                    const int m_loc = wm + i * 16 + rq;       // +r, r=0..3
                    const int c  = m_loc >> 3;
                    const int cs = c ^ (n_loc & 15);
                    __bf16* dst = &tbuf[n_loc * 128 + cs * 8 + (m_loc & 7)];
                    __bf16 tmp[4];
#pragma unroll
                    for (int r = 0; r < 4; ++r) tmp[r] = (__bf16)(acc[i][j][r] + bv);
                    *(uint64_t*)dst = *(const uint64_t*)tmp;
                }
            }
            __syncthreads();
            {
                __bf16* vt = (__bf16*)C2;
                const int n_loc = tid & 127;
                const int cpart = tid >> 7;
                const long b = mblk >> 11;                    // batch
                const long t0 = mblk & 2047;
                const long h  = nblk - 2048 + n_loc;
                __bf16* gdst = vt + b * (1024L * 2048) + h * 2048 + t0;
#pragma unroll
                for (int s = 0; s < 8; ++s) {
                    int c  = cpart * 8 + s;
                    int cs = c ^ (n_loc & 15);
                    bf16x8 vchunk = *(const bf16x8*)&tbuf[n_loc * 128 + cs * 8];
                    *(bf16x8*)(gdst + c * 8) = vchunk;
                }
            }
        } else {
            // ---- Q/K path: normal [m][n] bf16 store ----
#pragma unroll
            for (int i = 0; i < 4; ++i) {
#pragma unroll
                for (int j = 0; j < 4; ++j) {
                    const int n = nblk + wn + j * 16 + rsel;
                    __bf16* C = (n < 1024) ? (__bf16*)C0 : (__bf16*)C1;
                    const int col = n & 1023;
                    float bv = bias[n];
#pragma unroll
                    for (int r = 0; r < 4; ++r) {
                        int m = mblk + wm + i * 16 + rq + r;
                        C[(long)m * ldc + col] = (__bf16)(acc[i][j][r] + bv);
                    }
                }
            }
        }
    } else if constexpr (MODE == 1) {
        // ---- scores path: bf16 = acc * scale into workspace ----
        __bf16* C = (__bf16*)C0 + (long)z * sC;
#pragma unroll
        for (int i = 0; i < 4; ++i) {
#pragma unroll
            for (int j = 0; j < 4; ++j) {
                const int n = nblk + wn + j * 16 + rsel;
#pragma unroll
                for (int r = 0; r < 4; ++r) {
                    int m = mblk + wm + i * 16 + rq + r;
                    C[(long)m * ldc + n] = (__bf16)(acc[i][j][r] * scale);
                }
            }
        }
    } else {
        float* C = (float*)C0 + (long)z * sC;
#pragma unroll
        for (int i = 0; i < 4; ++i) {
#pragma unroll
            for (int j = 0; j < 4; ++j) {
                const int n = nblk + wn + j * 16 + rsel;
#pragma unroll
                for (int r = 0; r < 4; ++r) {
                    int m = mblk + wm + i * 16 + rq + r;
                    C[(long)m * ldc + n] = acc[i][j][r];
                }
            }
        }
    }
}

// --------- row softmax: bf16 scores in (p_bf) -> f32 P out + bf16 in-place -
__global__ __launch_bounds__(256) void softmax_rows(
        __bf16* __restrict__ Pb, float* __restrict__ P) {
    const long row = blockIdx.x;
    __bf16* pb = Pb + row * 2048;
    float*  p  = P  + row * 2048;
    const int tid  = threadIdx.x;
    const int lane = tid & 63;
    const int wave = tid >> 6;

    bf16x8 v = ((const bf16x8*)pb)[tid];
    float e[8];
#pragma unroll
    for (int i = 0; i < 8; ++i) e[i] = (float)v[i];

    float mx = e[0];
#pragma unroll
    for (int i = 1; i < 8; ++i) mx = fmaxf(mx, e[i]);
#pragma unroll
    for (int o = 1; o < 64; o <<= 1) mx = fmaxf(mx, __shfl_xor(mx, o, 64));

    __shared__ float redm[4], reds[4];
    if (lane == 0) redm[wave] = mx;
    __syncthreads();
    mx = fmaxf(fmaxf(redm[0], redm[1]), fmaxf(redm[2], redm[3]));

    float sum = 0.f;
#pragma unroll
    for (int i = 0; i < 8; ++i) { e[i] = __expf(e[i] - mx); sum += e[i]; }
#pragma unroll
    for (int o = 1; o < 64; o <<= 1) sum += __shfl_xor(sum, o, 64);
    if (lane == 0) reds[wave] = sum;
    __syncthreads();
    sum = reds[0] + reds[1] + reds[2] + reds[3];
    const float inv = 1.f / sum;

    float4 o0, o1;
    o0.x = e[0] * inv; o0.y = e[1] * inv; o0.z = e[2] * inv; o0.w = e[3] * inv;
    o1.x = e[4] * inv; o1.y = e[5] * inv; o1.z = e[6] * inv; o1.w = e[7] * inv;
    ((float4*)p)[tid * 2]     = o0;
    ((float4*)p)[tid * 2 + 1] = o1;
    bf16x8 ob;
    ob[0] = (__bf16)o0.x; ob[1] = (__bf16)o0.y; ob[2] = (__bf16)o0.z; ob[3] = (__bf16)o0.w;
    ob[4] = (__bf16)o1.x; ob[5] = (__bf16)o1.y; ob[6] = (__bf16)o1.z; ob[7] = (__bf16)o1.w;
    ((bf16x8*)pb)[tid] = ob;
}

// ---------------------------------------------------------------------------
extern "C" void kernel_launch(void* const* d_in, const int* in_sizes, int n_in,
                              void* d_out, int out_size, void* d_ws, size_t ws_size,
                              hipStream_t stream) {
    const float* x  = (const float*)d_in[0];
    const float* Wq = (const float*)d_in[1];
    const float* bq = (const float*)d_in[2];
    const float* Wk = (const float*)d_in[3];
    const float* bk = (const float*)d_in[4];
    const float* Wv = (const float*)d_in[5];
    const float* bv = (const float*)d_in[6];

    const int  S = 2048, H = 1024, I = 1024, B = 4;
    const long MS = (long)B * S;
    float* out_ws  = (float*)d_out;
    float* out_att = (float*)d_out + (long)B * S * H;

    char* w = (char*)d_ws;
    __bf16* x_bf   = (__bf16*)w; w += MS * I * 2;
    __bf16* wqkv   = (__bf16*)w; w += (long)3 * H * I * 2;
    float*  bias3  = (float*)w;  w += 4096 * 4;
    __bf16* q_bf   = (__bf16*)w; w += MS * H * 2;
    __bf16* k_bf   = (__bf16*)w; w += MS * H * 2;
    __bf16* vt_bf  = (__bf16*)w; w += MS * H * 2;
    __bf16* p_bf   = (__bf16*)w; w += (long)B * S * S * 2;

    // 1) all converts + bias pack
    {
        long tot = 1048576 + 3 * 131072 + 384;
        cvt_all<<<dim3((unsigned)((tot + 255) / 256)), dim3(256), 0, stream>>>(
            x, Wq, Wk, Wv, bq, bk, bv, x_bf, wqkv, bias3);
    }

    // 2) fused QKV projection (V written pre-transposed): M=8192, N=3072, K=1024
    gemm_nt<0><<<dim3(24, 64, 1), dim3(256), 0, stream>>>(
        x_bf, wqkv, q_bf, k_bf, vt_bf, bias3,
        1024, 1024, 1024, 0, 0, 0, 1024, 1.f);

    // 3) scores = Q K^T * 1/32 -> bf16 into p_bf workspace
    gemm_nt<1><<<dim3(16, 16, 4), dim3(256), 0, stream>>>(
        q_bf, k_bf, p_bf, nullptr, nullptr, nullptr,
        1024, 1024, 2048, (long)S * H, (long)S * H, (long)S * S, 1024, 0.03125f);

    // 4) softmax rows: bf16 scores in -> f32 P to output + bf16 P in-place
    softmax_rows<<<dim3(8192), dim3(256), 0, stream>>>(p_bf, out_att);

    // 5) weighted_sum = P V : M=2048, N=1024, K=2048 per batch
    gemm_nt<2><<<dim3(8, 16, 4), dim3(256), 0, stream>>>(
        p_bf, vt_bf, out_ws, nullptr, nullptr, nullptr,
        2048, 2048, 1024, (long)S * S, (long)S * H, (long)S * H, 2048, 1.f);
}

// Round 7
// 291.586 us; speedup vs baseline: 1.0617x; 1.0173x over previous
//
#include <hip/hip_runtime.h>
#include <hip/hip_bf16.h>
#include <cstdint>

// ---------------------------------------------------------------------------
// SelfAttention: q,k,v = x@W{q,k,v}^T + b ; P = softmax(qk^T/sqrt(H)) ; out = P@v
// B=4, S=2048, H=I=1024. fp32 I/O, bf16 MFMA internally (tol 6.25e-3).
// R11: softmax kernel eliminated via epilogue fusion.
//   scores GEMM epilogue: E = exp(s) (no max-subtract; |s|<~6 so safe),
//     bf16 E -> p_bf, per-row partial sums -> psum[z][32][2048] (in dead x_bf).
//   PV: prologue builds linv[128] = 1/rowsum in LDS; in-loop, each block
//     writes the f32 attention-weights for its owned k-chunks
//     ((k0>>6)&7 == blockIdx.x) from its staged E tile * linv; epilogue
//     scales acc by linv (out = (Sum E*V)/rowsum).
//   Saves softmax's 134 MB pass (~22 us) at the cost of +67 MB writes in PV.
// ---------------------------------------------------------------------------

typedef __bf16 bf16x8 __attribute__((ext_vector_type(8)));
typedef float  f32x4  __attribute__((ext_vector_type(4)));

__device__ __forceinline__ void load_lds16(const __bf16* g, __bf16* l) {
    __builtin_amdgcn_global_load_lds(
        (const __attribute__((address_space(1))) void*)g,
        (__attribute__((address_space(3))) void*)l,
        16, 0, 0);
}

// ------------- merged fp32->bf16 converts + bias pack (1 launch) -----------
__global__ __launch_bounds__(256) void cvt_all(
        const float* __restrict__ x,
        const float* __restrict__ wq, const float* __restrict__ wk,
        const float* __restrict__ wv,
        const float* __restrict__ bq, const float* __restrict__ bk,
        const float* __restrict__ bv,
        __bf16* __restrict__ xb, __bf16* __restrict__ wb,
        float* __restrict__ bias3) {
    const long NX = 1048576, NW = 131072;
    long i = (long)blockIdx.x * 256 + threadIdx.x;
    const float* src; __bf16* dst; long c;
    if (i < NX) { src = x; dst = xb; c = i; }
    else if (i < NX + 3 * NW) {
        long j = i - NX;
        src = (j < NW) ? wq : (j < 2 * NW) ? wk : wv;
        c = j % NW;
        dst = wb + (j / NW) * (NW * 8);
    } else if (i < NX + 3 * NW + 384) {
        long cidx = i - (NX + 3 * NW);
        int seg = (int)(cidx >> 7);
        const float* bs = (seg == 0) ? bq : (seg == 1) ? bk : bv;
        long off = (cidx & 127) * 8;
        float4 a = *(const float4*)(bs + off);
        float4 b = *(const float4*)(bs + off + 4);
        *(float4*)(bias3 + cidx * 8)     = a;
        *(float4*)(bias3 + cidx * 8 + 4) = b;
        return;
    } else return;
    const float4* s4 = (const float4*)src;
    float4 a = s4[2 * c], b = s4[2 * c + 1];
    bf16x8 o;
    o[0] = (__bf16)a.x; o[1] = (__bf16)a.y; o[2] = (__bf16)a.z; o[3] = (__bf16)a.w;
    o[4] = (__bf16)b.x; o[5] = (__bf16)b.y; o[6] = (__bf16)b.z; o[7] = (__bf16)b.w;
    ((bf16x8*)dst)[c] = o;
}

// ---------------- NT bf16 GEMM: C[m,n] = sum_k A[m,k] * Bt[n,k] ------------
// 128x128 tile, BK=64, 4 waves (2x2 of 64x64), 16x16x32 MFMA, 4x4 frags/wave.
// LDS: 16B chunks, chunk (row,cs) holds cg = cs ^ (row&7).  Zero conflicts.
// MODE 0: fused QKV. n<2048 -> bf16=acc+bias to C0/C1 [m][n&1023];
//         n>=2048 -> V: LDS-transposed, written as vt[h][t] to C2.
// MODE 1: scores: bf16 E=exp(acc*scale) -> C0 (p_bf); row partial sums ->
//         C1 = psum[z][32][2048] (one writer per (z,nb2,row), no atomics).
// MODE 2: PV on unnormalized E: linv from psum (C1); in-loop writes f32
//         attention weights to C2 for owned k-chunks; epilogue f32 = acc*linv
//         -> C0 (weighted sum).
template <int MODE>
__global__ __launch_bounds__(256, 4) void gemm_nt(
        const __bf16* __restrict__ A, const __bf16* __restrict__ Bt,
        void* __restrict__ C0, void* __restrict__ C1, void* __restrict__ C2,
        const float* __restrict__ bias,
        int lda, int ldb, int ldc, long sA, long sB, long sC,
        int K, float scale) {
    __shared__ __bf16 smem[16384];      // lA | lB, reused as transpose buffer
    __shared__ float linv[128];         // MODE 2: per-row 1/sum
    __bf16* lA = smem;
    __bf16* lB = smem + 8192;

    const int tid  = threadIdx.x;
    const int lane = tid & 63;
    const int wave = tid >> 6;
    const int mblk = blockIdx.y * 128;
    const int nblk = blockIdx.x * 128;
    const int z    = blockIdx.z;
    A  += (long)z * sA;
    Bt += (long)z * sB;

    const int wm = (wave >> 1) * 64;
    const int wn = (wave & 1) * 64;

    f32x4 zero = {0.f, 0.f, 0.f, 0.f};
    f32x4 acc[4][4];
#pragma unroll
    for (int i = 0; i < 4; ++i)
#pragma unroll
        for (int j = 0; j < 4; ++j) acc[i][j] = zero;

    const int rsel = lane & 15;
    const int quad = lane >> 4;

    int srow[4], scol[4];
#pragma unroll
    for (int it = 0; it < 4; ++it) {
        int s  = tid + it * 256;
        srow[it] = s >> 3;
        scol[it] = ((s & 7) ^ (srow[it] & 7)) * 8;
    }

    if constexpr (MODE == 2) {
        // build linv[128] = 1/rowsum from 32 partials (coalesced, L2-hot)
        if (tid < 128) {
            const float* ps = (const float*)C1 + (long)z * 65536 + (mblk + tid);
            float ssum = 0.f;
#pragma unroll
            for (int nb = 0; nb < 32; ++nb) ssum += ps[nb * 2048];
            linv[tid] = 1.f / ssum;
        }
        // first in-loop __syncthreads() publishes linv before any use
    }

    for (int k0 = 0; k0 < K; k0 += 64) {
#pragma unroll
        for (int it = 0; it < 4; ++it) {
            int s = tid + it * 256;
            load_lds16(A  + (long)(mblk + srow[it]) * lda + k0 + scol[it], lA + s * 8);
            load_lds16(Bt + (long)(nblk + srow[it]) * ldb + k0 + scol[it], lB + s * 8);
        }
        __syncthreads();

#pragma unroll
        for (int half = 0; half < 2; ++half) {
            const int cq = quad + half * 4;
            bf16x8 fa[4], fb[4];
#pragma unroll
            for (int i = 0; i < 4; ++i) {
                int ra = wm + i * 16 + rsel;
                fa[i] = *(const bf16x8*)&lA[(ra * 8 + (cq ^ (ra & 7))) * 8];
                int rb = wn + i * 16 + rsel;
                fb[i] = *(const bf16x8*)&lB[(rb * 8 + (cq ^ (rb & 7))) * 8];
            }
#pragma unroll
            for (int i = 0; i < 4; ++i)
#pragma unroll
                for (int j = 0; j < 4; ++j)
                    acc[i][j] = __builtin_amdgcn_mfma_f32_16x16x32_bf16(
                        fa[i], fb[j], acc[i][j], 0, 0, 0);
        }

        if constexpr (MODE == 2) {
            // write f32 attention weights for owned k-chunk from staged E tile
            if (((k0 >> 6) & 7) == (int)blockIdx.x) {
                float* wout = (float*)C2 + (long)z * (2048L * 2048);
#pragma unroll
                for (int it = 0; it < 4; ++it) {
                    int s = tid + it * 256;
                    bf16x8 ch = *(const bf16x8*)&lA[s * 8];
                    float iv = linv[srow[it]];
                    float4 w0, w1;
                    w0.x = (float)ch[0] * iv; w0.y = (float)ch[1] * iv;
                    w0.z = (float)ch[2] * iv; w0.w = (float)ch[3] * iv;
                    w1.x = (float)ch[4] * iv; w1.y = (float)ch[5] * iv;
                    w1.z = (float)ch[6] * iv; w1.w = (float)ch[7] * iv;
                    float* wp = wout + (long)(mblk + srow[it]) * 2048 + k0 + scol[it];
                    *(float4*)wp       = w0;
                    *(float4*)(wp + 4) = w1;
                }
            }
        }
        __syncthreads();
    }

    // epilogue: lane holds C[m = wm+i*16+quad*4+r][n = wn+j*16+rsel]
    const int rq = quad * 4;
    if constexpr (MODE == 0) {
        if (nblk >= 2048) {
            // ---- V path: transpose tile via LDS, store vt[h][t] ----
            __bf16* tbuf = smem;
#pragma unroll
            for (int i = 0; i < 4; ++i) {
#pragma unroll
                for (int j = 0; j < 4; ++j) {
                    const int n_loc = wn + j * 16 + rsel;
                    const float bv = bias[nblk + n_loc];
                    const int m_loc = wm + i * 16 + rq;       // +r, r=0..3
                    const int c  = m_loc >> 3;
                    const int cs = c ^ (n_loc & 15);
                    __bf16* dst = &tbuf[n_loc * 128 + cs * 8 + (m_loc & 7)];
                    __bf16 tmp[4];
#pragma unroll
                    for (int r = 0; r < 4; ++r) tmp[r] = (__bf16)(acc[i][j][r] + bv);
                    *(uint64_t*)dst = *(const uint64_t*)tmp;
                }
            }
            __syncthreads();
            {
                __bf16* vt = (__bf16*)C2;
                const int n_loc = tid & 127;
                const int cpart = tid >> 7;
                const long b = mblk >> 11;                    // batch
                const long t0 = mblk & 2047;
                const long h  = nblk - 2048 + n_loc;
                __bf16* gdst = vt + b * (1024L * 2048) + h * 2048 + t0;
#pragma unroll
                for (int s = 0; s < 8; ++s) {
                    int c  = cpart * 8 + s;
                    int cs = c ^ (n_loc & 15);
                    bf16x8 vchunk = *(const bf16x8*)&tbuf[n_loc * 128 + cs * 8];
                    *(bf16x8*)(gdst + c * 8) = vchunk;
                }
            }
        } else {
            // ---- Q/K path: normal [m][n] bf16 store ----
#pragma unroll
            for (int i = 0; i < 4; ++i) {
#pragma unroll
                for (int j = 0; j < 4; ++j) {
                    const int n = nblk + wn + j * 16 + rsel;
                    __bf16* C = (n < 1024) ? (__bf16*)C0 : (__bf16*)C1;
                    const int col = n & 1023;
                    float bv = bias[n];
#pragma unroll
                    for (int r = 0; r < 4; ++r) {
                        int m = mblk + wm + i * 16 + rq + r;
                        C[(long)m * ldc + col] = (__bf16)(acc[i][j][r] + bv);
                    }
                }
            }
        }
    } else if constexpr (MODE == 1) {
        // ---- scores path: E = exp(s) bf16 + per-row partial sums ----
        __bf16* C = (__bf16*)C0 + (long)z * sC;
        float* psum = (float*)C1 + (long)z * 65536;   // [32][2048]
        float vsum[4][4];
#pragma unroll
        for (int i = 0; i < 4; ++i)
#pragma unroll
            for (int r = 0; r < 4; ++r) vsum[i][r] = 0.f;
#pragma unroll
        for (int i = 0; i < 4; ++i) {
#pragma unroll
            for (int j = 0; j < 4; ++j) {
                const int n = nblk + wn + j * 16 + rsel;
#pragma unroll
                for (int r = 0; r < 4; ++r) {
                    int m = mblk + wm + i * 16 + rq + r;
                    float e = __expf(acc[i][j][r] * scale);
                    C[(long)m * ldc + n] = (__bf16)e;
                    vsum[i][r] += e;
                }
            }
        }
        // reduce over the 16 rsel lanes (cols) -> row sums over this wave's 64 cols
#pragma unroll
        for (int o = 1; o < 16; o <<= 1)
#pragma unroll
            for (int i = 0; i < 4; ++i)
#pragma unroll
                for (int r = 0; r < 4; ++r)
                    vsum[i][r] += __shfl_xor(vsum[i][r], o, 64);
        if (rsel == 0) {
            const int nb2 = (nblk + wn) >> 6;             // 0..31
#pragma unroll
            for (int i = 0; i < 4; ++i)
#pragma unroll
                for (int r = 0; r < 4; ++r)
                    psum[nb2 * 2048 + mblk + wm + i * 16 + rq + r] = vsum[i][r];
        }
    } else {
        // ---- PV path: out = acc * linv (normalized weighted sum) ----
        float* Cz = (float*)C0 + (long)z * sC;
#pragma unroll
        for (int i = 0; i < 4; ++i) {
#pragma unroll
            for (int j = 0; j < 4; ++j) {
                const int n = nblk + wn + j * 16 + rsel;
#pragma unroll
                for (int r = 0; r < 4; ++r) {
                    int m = mblk + wm + i * 16 + rq + r;
                    Cz[(long)m * ldc + n] = acc[i][j][r] * linv[wm + i * 16 + rq + r];
                }
            }
        }
    }
}

// ---------------------------------------------------------------------------
extern "C" void kernel_launch(void* const* d_in, const int* in_sizes, int n_in,
                              void* d_out, int out_size, void* d_ws, size_t ws_size,
                              hipStream_t stream) {
    const float* x  = (const float*)d_in[0];
    const float* Wq = (const float*)d_in[1];
    const float* bq = (const float*)d_in[2];
    const float* Wk = (const float*)d_in[3];
    const float* bk = (const float*)d_in[4];
    const float* Wv = (const float*)d_in[5];
    const float* bv = (const float*)d_in[6];

    const int  S = 2048, H = 1024, I = 1024, B = 4;
    const long MS = (long)B * S;
    float* out_ws  = (float*)d_out;
    float* out_att = (float*)d_out + (long)B * S * H;

    char* w = (char*)d_ws;
    __bf16* x_bf   = (__bf16*)w; w += MS * I * 2;
    __bf16* wqkv   = (__bf16*)w; w += (long)3 * H * I * 2;
    float*  bias3  = (float*)w;  w += 4096 * 4;
    __bf16* q_bf   = (__bf16*)w; w += MS * H * 2;
    __bf16* k_bf   = (__bf16*)w; w += MS * H * 2;
    __bf16* vt_bf  = (__bf16*)w; w += MS * H * 2;
    __bf16* p_bf   = (__bf16*)w; w += (long)B * S * S * 2;
    // psum [4][32][2048] f32 = 1 MB carved from x_bf (dead after QKV)
    float* psum = (float*)x_bf;

    // 1) all converts + bias pack
    {
        long tot = 1048576 + 3 * 131072 + 384;
        cvt_all<<<dim3((unsigned)((tot + 255) / 256)), dim3(256), 0, stream>>>(
            x, Wq, Wk, Wv, bq, bk, bv, x_bf, wqkv, bias3);
    }

    // 2) fused QKV projection (V written pre-transposed): M=8192, N=3072, K=1024
    gemm_nt<0><<<dim3(24, 64, 1), dim3(256), 0, stream>>>(
        x_bf, wqkv, q_bf, k_bf, vt_bf, bias3,
        1024, 1024, 1024, 0, 0, 0, 1024, 1.f);

    // 3) scores: E = exp(QK^T/32) bf16 -> p_bf; row partial sums -> psum
    gemm_nt<1><<<dim3(16, 16, 4), dim3(256), 0, stream>>>(
        q_bf, k_bf, p_bf, psum, nullptr, nullptr,
        1024, 1024, 2048, (long)S * H, (long)S * H, (long)S * S, 1024, 0.03125f);

    // 4) PV on E: writes f32 attention weights (in-loop) + weighted sum (epi)
    gemm_nt<2><<<dim3(8, 16, 4), dim3(256), 0, stream>>>(
        p_bf, vt_bf, out_ws, psum, out_att, nullptr,
        2048, 2048, 1024, (long)S * S, (long)S * H, (long)S * H, 2048, 1.f);
}

// Round 8
// 284.346 us; speedup vs baseline: 1.0888x; 1.0255x over previous
//
#include <hip/hip_runtime.h>
#include <hip/hip_bf16.h>
#include <cstdint>

// ---------------------------------------------------------------------------
// SelfAttention: q,k,v = x@W{q,k,v}^T + b ; P = softmax(qk^T/sqrt(H)) ; out = P@v
// B=4, S=2048, H=I=1024. fp32 I/O, bf16 MFMA internally (tol 6.25e-3).
// R12: R11 (softmax folded into scores/PV epilogues) with PV's f32
//      attention-weight write moved from in-loop (vmcnt/barrier interference,
//      PV 67us @ MfmaUtil 20%) to the PV epilogue, re-reading E from global
//      (own-XCD L2-hot: ownership k0/64 in {x,x+8,x+16,x+24} is exactly the
//      chunks this block staged). Loop body = verified R9 structure.
// ---------------------------------------------------------------------------

typedef __bf16 bf16x8 __attribute__((ext_vector_type(8)));
typedef float  f32x4  __attribute__((ext_vector_type(4)));

__device__ __forceinline__ void load_lds16(const __bf16* g, __bf16* l) {
    __builtin_amdgcn_global_load_lds(
        (const __attribute__((address_space(1))) void*)g,
        (__attribute__((address_space(3))) void*)l,
        16, 0, 0);
}

// ------------- merged fp32->bf16 converts + bias pack (1 launch) -----------
__global__ __launch_bounds__(256) void cvt_all(
        const float* __restrict__ x,
        const float* __restrict__ wq, const float* __restrict__ wk,
        const float* __restrict__ wv,
        const float* __restrict__ bq, const float* __restrict__ bk,
        const float* __restrict__ bv,
        __bf16* __restrict__ xb, __bf16* __restrict__ wb,
        float* __restrict__ bias3) {
    const long NX = 1048576, NW = 131072;
    long i = (long)blockIdx.x * 256 + threadIdx.x;
    const float* src; __bf16* dst; long c;
    if (i < NX) { src = x; dst = xb; c = i; }
    else if (i < NX + 3 * NW) {
        long j = i - NX;
        src = (j < NW) ? wq : (j < 2 * NW) ? wk : wv;
        c = j % NW;
        dst = wb + (j / NW) * (NW * 8);
    } else if (i < NX + 3 * NW + 384) {
        long cidx = i - (NX + 3 * NW);
        int seg = (int)(cidx >> 7);
        const float* bs = (seg == 0) ? bq : (seg == 1) ? bk : bv;
        long off = (cidx & 127) * 8;
        float4 a = *(const float4*)(bs + off);
        float4 b = *(const float4*)(bs + off + 4);
        *(float4*)(bias3 + cidx * 8)     = a;
        *(float4*)(bias3 + cidx * 8 + 4) = b;
        return;
    } else return;
    const float4* s4 = (const float4*)src;
    float4 a = s4[2 * c], b = s4[2 * c + 1];
    bf16x8 o;
    o[0] = (__bf16)a.x; o[1] = (__bf16)a.y; o[2] = (__bf16)a.z; o[3] = (__bf16)a.w;
    o[4] = (__bf16)b.x; o[5] = (__bf16)b.y; o[6] = (__bf16)b.z; o[7] = (__bf16)b.w;
    ((bf16x8*)dst)[c] = o;
}

// ---------------- NT bf16 GEMM: C[m,n] = sum_k A[m,k] * Bt[n,k] ------------
// 128x128 tile, BK=64, 4 waves (2x2 of 64x64), 16x16x32 MFMA, 4x4 frags/wave.
// LDS: 16B chunks, chunk (row,cs) holds cg = cs ^ (row&7).  Zero conflicts.
// MODE 0: fused QKV. n<2048 -> bf16=acc+bias to C0/C1 [m][n&1023];
//         n>=2048 -> V: LDS-transposed, written as vt[h][t] to C2.
// MODE 1: scores: bf16 E=exp(acc*scale) -> C0 (p_bf); row partial sums ->
//         C1 = psum[z][32][2048] (one writer per (z,nb2,row), no atomics).
// MODE 2: PV on unnormalized E: linv from psum (C1); epilogue writes f32
//         attention weights to C2 for owned k-chunks (E re-read from global,
//         L2-hot) and f32 = acc*linv -> C0 (weighted sum).
template <int MODE>
__global__ __launch_bounds__(256, 4) void gemm_nt(
        const __bf16* __restrict__ A, const __bf16* __restrict__ Bt,
        void* __restrict__ C0, void* __restrict__ C1, void* __restrict__ C2,
        const float* __restrict__ bias,
        int lda, int ldb, int ldc, long sA, long sB, long sC,
        int K, float scale) {
    __shared__ __bf16 smem[16384];      // lA | lB, reused as transpose buffer
    __shared__ float linv[128];         // MODE 2: per-row 1/sum
    __bf16* lA = smem;
    __bf16* lB = smem + 8192;

    const int tid  = threadIdx.x;
    const int lane = tid & 63;
    const int wave = tid >> 6;
    const int mblk = blockIdx.y * 128;
    const int nblk = blockIdx.x * 128;
    const int z    = blockIdx.z;
    A  += (long)z * sA;
    Bt += (long)z * sB;

    const int wm = (wave >> 1) * 64;
    const int wn = (wave & 1) * 64;

    f32x4 zero = {0.f, 0.f, 0.f, 0.f};
    f32x4 acc[4][4];
#pragma unroll
    for (int i = 0; i < 4; ++i)
#pragma unroll
        for (int j = 0; j < 4; ++j) acc[i][j] = zero;

    const int rsel = lane & 15;
    const int quad = lane >> 4;

    int srow[4], scol[4];
#pragma unroll
    for (int it = 0; it < 4; ++it) {
        int s  = tid + it * 256;
        srow[it] = s >> 3;
        scol[it] = ((s & 7) ^ (srow[it] & 7)) * 8;
    }

    if constexpr (MODE == 2) {
        // build linv[128] = 1/rowsum from 32 partials (coalesced, L2-hot)
        if (tid < 128) {
            const float* ps = (const float*)C1 + (long)z * 65536 + (mblk + tid);
            float ssum = 0.f;
#pragma unroll
            for (int nb = 0; nb < 32; ++nb) ssum += ps[nb * 2048];
            linv[tid] = 1.f / ssum;
        }
        // first in-loop __syncthreads() publishes linv before any use
    }

    for (int k0 = 0; k0 < K; k0 += 64) {
#pragma unroll
        for (int it = 0; it < 4; ++it) {
            int s = tid + it * 256;
            load_lds16(A  + (long)(mblk + srow[it]) * lda + k0 + scol[it], lA + s * 8);
            load_lds16(Bt + (long)(nblk + srow[it]) * ldb + k0 + scol[it], lB + s * 8);
        }
        __syncthreads();

#pragma unroll
        for (int half = 0; half < 2; ++half) {
            const int cq = quad + half * 4;
            bf16x8 fa[4], fb[4];
#pragma unroll
            for (int i = 0; i < 4; ++i) {
                int ra = wm + i * 16 + rsel;
                fa[i] = *(const bf16x8*)&lA[(ra * 8 + (cq ^ (ra & 7))) * 8];
                int rb = wn + i * 16 + rsel;
                fb[i] = *(const bf16x8*)&lB[(rb * 8 + (cq ^ (rb & 7))) * 8];
            }
#pragma unroll
            for (int i = 0; i < 4; ++i)
#pragma unroll
                for (int j = 0; j < 4; ++j)
                    acc[i][j] = __builtin_amdgcn_mfma_f32_16x16x32_bf16(
                        fa[i], fb[j], acc[i][j], 0, 0, 0);
        }
        __syncthreads();
    }

    // epilogue: lane holds C[m = wm+i*16+quad*4+r][n = wn+j*16+rsel]
    const int rq = quad * 4;
    if constexpr (MODE == 0) {
        if (nblk >= 2048) {
            // ---- V path: transpose tile via LDS, store vt[h][t] ----
            __bf16* tbuf = smem;
#pragma unroll
            for (int i = 0; i < 4; ++i) {
#pragma unroll
                for (int j = 0; j < 4; ++j) {
                    const int n_loc = wn + j * 16 + rsel;
                    const float bv = bias[nblk + n_loc];
                    const int m_loc = wm + i * 16 + rq;       // +r, r=0..3
                    const int c  = m_loc >> 3;
                    const int cs = c ^ (n_loc & 15);
                    __bf16* dst = &tbuf[n_loc * 128 + cs * 8 + (m_loc & 7)];
                    __bf16 tmp[4];
#pragma unroll
                    for (int r = 0; r < 4; ++r) tmp[r] = (__bf16)(acc[i][j][r] + bv);
                    *(uint64_t*)dst = *(const uint64_t*)tmp;
                }
            }
            __syncthreads();
            {
                __bf16* vt = (__bf16*)C2;
                const int n_loc = tid & 127;
                const int cpart = tid >> 7;
                const long b = mblk >> 11;                    // batch
                const long t0 = mblk & 2047;
                const long h  = nblk - 2048 + n_loc;
                __bf16* gdst = vt + b * (1024L * 2048) + h * 2048 + t0;
#pragma unroll
                for (int s = 0; s < 8; ++s) {
                    int c  = cpart * 8 + s;
                    int cs = c ^ (n_loc & 15);
                    bf16x8 vchunk = *(const bf16x8*)&tbuf[n_loc * 128 + cs * 8];
                    *(bf16x8*)(gdst + c * 8) = vchunk;
                }
            }
        } else {
            // ---- Q/K path: normal [m][n] bf16 store ----
#pragma unroll
            for (int i = 0; i < 4; ++i) {
#pragma unroll
                for (int j = 0; j < 4; ++j) {
                    const int n = nblk + wn + j * 16 + rsel;
                    __bf16* C = (n < 1024) ? (__bf16*)C0 : (__bf16*)C1;
                    const int col = n & 1023;
                    float bv = bias[n];
#pragma unroll
                    for (int r = 0; r < 4; ++r) {
                        int m = mblk + wm + i * 16 + rq + r;
                        C[(long)m * ldc + col] = (__bf16)(acc[i][j][r] + bv);
                    }
                }
            }
        }
    } else if constexpr (MODE == 1) {
        // ---- scores path: E = exp(s) bf16 + per-row partial sums ----
        __bf16* C = (__bf16*)C0 + (long)z * sC;
        float* psum = (float*)C1 + (long)z * 65536;   // [32][2048]
        float vsum[4][4];
#pragma unroll
        for (int i = 0; i < 4; ++i)
#pragma unroll
            for (int r = 0; r < 4; ++r) vsum[i][r] = 0.f;
#pragma unroll
        for (int i = 0; i < 4; ++i) {
#pragma unroll
            for (int j = 0; j < 4; ++j) {
                const int n = nblk + wn + j * 16 + rsel;
#pragma unroll
                for (int r = 0; r < 4; ++r) {
                    int m = mblk + wm + i * 16 + rq + r;
                    float e = __expf(acc[i][j][r] * scale);
                    C[(long)m * ldc + n] = (__bf16)e;
                    vsum[i][r] += e;
                }
            }
        }
        // reduce over the 16 rsel lanes (cols) -> row sums over this wave's 64 cols
#pragma unroll
        for (int o = 1; o < 16; o <<= 1)
#pragma unroll
            for (int i = 0; i < 4; ++i)
#pragma unroll
                for (int r = 0; r < 4; ++r)
                    vsum[i][r] += __shfl_xor(vsum[i][r], o, 64);
        if (rsel == 0) {
            const int nb2 = (nblk + wn) >> 6;             // 0..31
#pragma unroll
            for (int i = 0; i < 4; ++i)
#pragma unroll
                for (int r = 0; r < 4; ++r)
                    psum[nb2 * 2048 + mblk + wm + i * 16 + rq + r] = vsum[i][r];
        }
    } else {
        // ---- PV path ----
        // (a) f32 attention-weight write for owned k-chunks; E re-read from
        //     global (own-XCD L2-hot: this block staged exactly these chunks).
        {
            float* wout = (float*)C2 + (long)z * (2048L * 2048);
#pragma unroll
            for (int kc = 0; kc < 4; ++kc) {
                const int k0 = ((int)blockIdx.x + kc * 8) << 6;
#pragma unroll
                for (int it = 0; it < 4; ++it) {
                    const __bf16* ep = A + (long)(mblk + srow[it]) * lda + k0 + scol[it];
                    bf16x8 ch = *(const bf16x8*)ep;
                    const float iv = linv[srow[it]];
                    float4 w0, w1;
                    w0.x = (float)ch[0] * iv; w0.y = (float)ch[1] * iv;
                    w0.z = (float)ch[2] * iv; w0.w = (float)ch[3] * iv;
                    w1.x = (float)ch[4] * iv; w1.y = (float)ch[5] * iv;
                    w1.z = (float)ch[6] * iv; w1.w = (float)ch[7] * iv;
                    float* wp = wout + (long)(mblk + srow[it]) * 2048 + k0 + scol[it];
                    *(float4*)wp       = w0;
                    *(float4*)(wp + 4) = w1;
                }
            }
        }
        // (b) weighted sum: out = acc * linv
        float* Cz = (float*)C0 + (long)z * sC;
#pragma unroll
        for (int i = 0; i < 4; ++i) {
#pragma unroll
            for (int j = 0; j < 4; ++j) {
                const int n = nblk + wn + j * 16 + rsel;
#pragma unroll
                for (int r = 0; r < 4; ++r) {
                    int m = mblk + wm + i * 16 + rq + r;
                    Cz[(long)m * ldc + n] = acc[i][j][r] * linv[wm + i * 16 + rq + r];
                }
            }
        }
    }
}

// ---------------------------------------------------------------------------
extern "C" void kernel_launch(void* const* d_in, const int* in_sizes, int n_in,
                              void* d_out, int out_size, void* d_ws, size_t ws_size,
                              hipStream_t stream) {
    const float* x  = (const float*)d_in[0];
    const float* Wq = (const float*)d_in[1];
    const float* bq = (const float*)d_in[2];
    const float* Wk = (const float*)d_in[3];
    const float* bk = (const float*)d_in[4];
    const float* Wv = (const float*)d_in[5];
    const float* bv = (const float*)d_in[6];

    const int  S = 2048, H = 1024, I = 1024, B = 4;
    const long MS = (long)B * S;
    float* out_ws  = (float*)d_out;
    float* out_att = (float*)d_out + (long)B * S * H;

    char* w = (char*)d_ws;
    __bf16* x_bf   = (__bf16*)w; w += MS * I * 2;
    __bf16* wqkv   = (__bf16*)w; w += (long)3 * H * I * 2;
    float*  bias3  = (float*)w;  w += 4096 * 4;
    __bf16* q_bf   = (__bf16*)w; w += MS * H * 2;
    __bf16* k_bf   = (__bf16*)w; w += MS * H * 2;
    __bf16* vt_bf  = (__bf16*)w; w += MS * H * 2;
    __bf16* p_bf   = (__bf16*)w; w += (long)B * S * S * 2;
    // psum [4][32][2048] f32 = 1 MB carved from x_bf (dead after QKV)
    float* psum = (float*)x_bf;

    // 1) all converts + bias pack
    {
        long tot = 1048576 + 3 * 131072 + 384;
        cvt_all<<<dim3((unsigned)((tot + 255) / 256)), dim3(256), 0, stream>>>(
            x, Wq, Wk, Wv, bq, bk, bv, x_bf, wqkv, bias3);
    }

    // 2) fused QKV projection (V written pre-transposed): M=8192, N=3072, K=1024
    gemm_nt<0><<<dim3(24, 64, 1), dim3(256), 0, stream>>>(
        x_bf, wqkv, q_bf, k_bf, vt_bf, bias3,
        1024, 1024, 1024, 0, 0, 0, 1024, 1.f);

    // 3) scores: E = exp(QK^T/32) bf16 -> p_bf; row partial sums -> psum
    gemm_nt<1><<<dim3(16, 16, 4), dim3(256), 0, stream>>>(
        q_bf, k_bf, p_bf, psum, nullptr, nullptr,
        1024, 1024, 2048, (long)S * H, (long)S * H, (long)S * S, 1024, 0.03125f);

    // 4) PV on E: epilogue writes f32 attention weights + weighted sum
    gemm_nt<2><<<dim3(8, 16, 4), dim3(256), 0, stream>>>(
        p_bf, vt_bf, out_ws, psum, out_att, nullptr,
        2048, 2048, 1024, (long)S * S, (long)S * H, (long)S * H, 2048, 1.f);
}